// Round 3
// baseline (1003.632 us; speedup 1.0000x reference)
//
#include <hip/hip_runtime.h>
#include <hip/hip_bf16.h>

#define GG   256
#define NPGD 192
#define NN   (GG*NPGD)    // 49152 nodes
#define DDIM 128
#define EE   786432
#define HH   8

typedef __attribute__((ext_vector_type(8))) short short8;
typedef __attribute__((ext_vector_type(4))) float f32x4;

__device__ __forceinline__ float bn_rsq() { return 0.9999950000374996f; } // 1/sqrt(1+1e-5)

// ---------------- prep: histogram (blocks 0..3071) + weight f32->bf16 (blocks 3072..3231) ----------------
__global__ __launch_bounds__(256) void k_prep(
    const int* __restrict__ dst, int* __restrict__ cnt,
    const float* __restrict__ gw1, const float* __restrict__ gw2,
    const float* __restrict__ ipw, const float* __restrict__ opw,
    const float* __restrict__ fw1, const float* __restrict__ fw2,
    __hip_bfloat16* __restrict__ wb)
{
    const int b = blockIdx.x;
    if (b < 3072) {
        int e = b * 256 + threadIdx.x;
        atomicAdd(&cnt[dst[e]], 1);
        return;
    }
    int g = (b - 3072) * 1024 + threadIdx.x * 4;
    const float* s; int off;
    if      (g <  16384) { s = gw1; off = 0; }
    else if (g <  32768) { s = gw2; off = 16384; }
    else if (g <  81920) { s = ipw; off = 32768; }
    else if (g <  98304) { s = opw; off = 81920; }
    else if (g < 131072) { s = fw1; off = 98304; }
    else                 { s = fw2; off = 131072; }
    float4 f = *(const float4*)&s[g - off];
    wb[g]     = __float2bfloat16(f.x);
    wb[g + 1] = __float2bfloat16(f.y);
    wb[g + 2] = __float2bfloat16(f.z);
    wb[g + 3] = __float2bfloat16(f.w);
}

// ---------------- exclusive prefix scan over 49152 counts (1 block) ----------------
__global__ __launch_bounds__(1024) void k_scan(const int* __restrict__ cnt,
                                               int* __restrict__ offp, int* __restrict__ cur) {
    __shared__ int part[1024];
    const int t = threadIdx.x;
    const int4* c4 = (const int4*)cnt;
    int4 v[12];
    int s = 0;
#pragma unroll
    for (int i = 0; i < 12; ++i) {
        v[i] = c4[t * 12 + i];
        s += v[i].x + v[i].y + v[i].z + v[i].w;
    }
    part[t] = s;
    __syncthreads();
    for (int d = 1; d < 1024; d <<= 1) {
        int u = (t >= d) ? part[t - d] : 0;
        __syncthreads();
        part[t] += u;
        __syncthreads();
    }
    int pre = (t == 0) ? 0 : part[t - 1];
    int4* o4 = (int4*)offp;
    int4* u4 = (int4*)cur;
#pragma unroll
    for (int i = 0; i < 12; ++i) {
        int4 a = v[i], o;
        o.x = pre; pre += a.x;
        o.y = pre; pre += a.y;
        o.z = pre; pre += a.z;
        o.w = pre; pre += a.w;
        o4[t * 12 + i] = o;
        u4[t * 12 + i] = o;
    }
    if (t == 1023) offp[NN] = pre;
}

// ---------------- scatter: CSR payload {edge_id, src} ----------------
__global__ __launch_bounds__(256) void k_scatter(const int* __restrict__ dst, const int* __restrict__ src,
                                                 int* __restrict__ cur, int2* __restrict__ ecsr) {
    int e = blockIdx.x * 256 + threadIdx.x;
    int p = atomicAdd(&cur[dst[e]], 1);
    ecsr[p] = make_int2(e, src[e]);
}

// ---------------- GINE aggregate: z = x + sum_in relu(x[src]+e); also emit x_bf16 ----------------
// INSTRUMENTED: host passes rep (=6); body is pure so repeats are idempotent.
// asm opacity keeps the compiler from collapsing the repeats (DCE/CSE).
__global__ __launch_bounds__(256) void k_aggr(
    const float* __restrict__ x, const float* __restrict__ ea,
    const int* __restrict__ offp, const int2* __restrict__ ecsr,
    __hip_bfloat16* __restrict__ z, __hip_bfloat16* __restrict__ xb, int rep)
{
    const int w = threadIdx.x >> 6, l = threadIdx.x & 63;
    const int v = blockIdx.x * 4 + w;
    const int c = l * 2;
    const int b = offp[v], e = offp[v + 1];
    for (int r = 0; r < rep; ++r) {
        float ax = 0.f, ay = 0.f;
        asm volatile("" : "+v"(ax), "+v"(ay));
        int i = b;
        for (; i + 2 <= e; i += 2) {
            const int2 p0 = ecsr[i];
            const int2 p1 = ecsr[i + 1];
            const float2 a0 = *(const float2*)&ea[(size_t)p0.x * DDIM + c];
            const float2 x0 = *(const float2*)&x[(size_t)p0.y * DDIM + c];
            const float2 a1 = *(const float2*)&ea[(size_t)p1.x * DDIM + c];
            const float2 x1 = *(const float2*)&x[(size_t)p1.y * DDIM + c];
            ax += fmaxf(a0.x + x0.x, 0.f) + fmaxf(a1.x + x1.x, 0.f);
            ay += fmaxf(a0.y + x0.y, 0.f) + fmaxf(a1.y + x1.y, 0.f);
        }
        if (i < e) {
            const int2 p0 = ecsr[i];
            const float2 a0 = *(const float2*)&ea[(size_t)p0.x * DDIM + c];
            const float2 x0 = *(const float2*)&x[(size_t)p0.y * DDIM + c];
            ax += fmaxf(a0.x + x0.x, 0.f);
            ay += fmaxf(a0.y + x0.y, 0.f);
        }
        const float2 xv = *(const float2*)&x[(size_t)v * DDIM + c];
        __hip_bfloat162 zz, xx;
        zz.x = __float2bfloat16(xv.x + ax); zz.y = __float2bfloat16(xv.y + ay);
        xx.x = __float2bfloat16(xv.x);      xx.y = __float2bfloat16(xv.y);
        *(__hip_bfloat162*)&z[(size_t)v * DDIM + c]  = zz;
        *(__hip_bfloat162*)&xb[(size_t)v * DDIM + c] = xx;
    }
}

// ---------------- generic bf16 MFMA GEMM (weights from global/L2): out = epi(A @ W^T + b) ----------------
// MODE 2: bias only -> bf16 (in_proj)    MODE 3: bn1g(x + .) + h_local -> bf16 (out_proj)
template<int K, int OUTD, int MODE>
__global__ __launch_bounds__(256) void k_gemm(
    const __hip_bfloat16* __restrict__ A, int lda,
    const __hip_bfloat16* __restrict__ W,
    const float* __restrict__ bias,
    void* __restrict__ out, int ldo,
    const float* __restrict__ xres,
    const __hip_bfloat16* __restrict__ resb,
    const float* __restrict__ bng, const float* __restrict__ bnb)
{
    const int tid = threadIdx.x;
    const int l = tid & 63, w = tid >> 6;
    const int row0 = blockIdx.x * 64 + w * 16;
    const int cl = l & 15;
    const int kg = (l >> 4) * 8;
    const int rg = (l >> 4) * 4;

    short8 af[K / 32];
#pragma unroll
    for (int f = 0; f < K / 32; ++f)
        af[f] = *(const short8*)&A[(size_t)(row0 + cl) * lda + f * 32 + kg];

#pragma unroll
    for (int ct = 0; ct < OUTD / 16; ++ct) {
        f32x4 acc = {0.f, 0.f, 0.f, 0.f};
#pragma unroll
        for (int f = 0; f < K / 32; ++f) {
            short8 bf = *(const short8*)&W[(size_t)(ct * 16 + cl) * K + f * 32 + kg];
            acc = __builtin_amdgcn_mfma_f32_16x16x32_bf16(af[f], bf, acc, 0, 0, 0);
        }
        const int c = ct * 16 + cl;
        const float bv = bias[c];
#pragma unroll
        for (int j = 0; j < 4; ++j) {
            const int r = row0 + rg + j;
            float v = acc[j] + bv;
            if constexpr (MODE == 2) {
                ((__hip_bfloat16*)out)[(size_t)r * ldo + c] = __float2bfloat16(v);
            } else {
                v += xres[(size_t)r * DDIM + c];
                v = bng[c] * v * bn_rsq() + bnb[c];
                v += __bfloat162float(resb[(size_t)r * DDIM + c]);
                ((__hip_bfloat16*)out)[(size_t)r * ldo + c] = __float2bfloat16(v);
            }
        }
    }
}

// ---------------- fused GIN MLP: out = bn1l(x + relu(z@W1^T+b1)@W2^T + b2) ----------------
__global__ __launch_bounds__(256) void k_gin(
    const __hip_bfloat16* __restrict__ A,
    const __hip_bfloat16* __restrict__ W1, const float* __restrict__ b1,
    const __hip_bfloat16* __restrict__ W2, const float* __restrict__ b2,
    const float* __restrict__ xres,
    const float* __restrict__ bng, const float* __restrict__ bnb,
    __hip_bfloat16* __restrict__ out)
{
    __shared__ __align__(16) __hip_bfloat16 hid[4][16 * 152];
    const int tid = threadIdx.x;
    const int l = tid & 63, w = tid >> 6;
    const int row0 = blockIdx.x * 64 + w * 16;
    const int cl = l & 15;
    const int kg = (l >> 4) * 8;
    const int rg = (l >> 4) * 4;

    short8 af[4];
#pragma unroll
    for (int f = 0; f < 4; ++f)
        af[f] = *(const short8*)&A[(size_t)(row0 + cl) * DDIM + f * 32 + kg];

#pragma unroll
    for (int ct = 0; ct < 8; ++ct) {
        f32x4 acc = {0.f, 0.f, 0.f, 0.f};
#pragma unroll
        for (int f = 0; f < 4; ++f) {
            short8 bf = *(const short8*)&W1[(size_t)(ct * 16 + cl) * DDIM + f * 32 + kg];
            acc = __builtin_amdgcn_mfma_f32_16x16x32_bf16(af[f], bf, acc, 0, 0, 0);
        }
        const float bv = b1[ct * 16 + cl];
#pragma unroll
        for (int j = 0; j < 4; ++j)
            hid[w][(rg + j) * 152 + ct * 16 + cl] = __float2bfloat16(fmaxf(acc[j] + bv, 0.f));
    }
    __syncthreads();

    short8 af2[4];
#pragma unroll
    for (int f = 0; f < 4; ++f)
        af2[f] = *(const short8*)&hid[w][cl * 152 + f * 32 + kg];

#pragma unroll
    for (int ct = 0; ct < 8; ++ct) {
        f32x4 acc = {0.f, 0.f, 0.f, 0.f};
#pragma unroll
        for (int f = 0; f < 4; ++f) {
            short8 bf = *(const short8*)&W2[(size_t)(ct * 16 + cl) * DDIM + f * 32 + kg];
            acc = __builtin_amdgcn_mfma_f32_16x16x32_bf16(af2[f], bf, acc, 0, 0, 0);
        }
        const int c = ct * 16 + cl;
        const float bv = b2[c];
#pragma unroll
        for (int j = 0; j < 4; ++j) {
            const int r = row0 + rg + j;
            float v = acc[j] + bv + xres[(size_t)r * DDIM + c];
            v = bng[c] * v * bn_rsq() + bnb[c];
            out[(size_t)r * DDIM + c] = __float2bfloat16(v);
        }
    }
}

// ---------------- fused FFN: d_out = bn2(h + relu(h@F1^T+b1)@F2^T + b2)  (fp32 out) ----------------
__global__ __launch_bounds__(256) void k_ffn(
    const __hip_bfloat16* __restrict__ A,
    const __hip_bfloat16* __restrict__ W1, const float* __restrict__ b1,
    const __hip_bfloat16* __restrict__ W2, const float* __restrict__ b2,
    const float* __restrict__ bng, const float* __restrict__ bnb,
    float* __restrict__ out)
{
    __shared__ __align__(16) __hip_bfloat16 hid[4][16 * 280];
    const int tid = threadIdx.x;
    const int l = tid & 63, w = tid >> 6;
    const int row0 = blockIdx.x * 64 + w * 16;
    const int cl = l & 15;
    const int kg = (l >> 4) * 8;
    const int rg = (l >> 4) * 4;

    short8 af[4];
#pragma unroll
    for (int f = 0; f < 4; ++f)
        af[f] = *(const short8*)&A[(size_t)(row0 + cl) * DDIM + f * 32 + kg];

#pragma unroll
    for (int ct = 0; ct < 16; ++ct) {
        f32x4 acc = {0.f, 0.f, 0.f, 0.f};
#pragma unroll
        for (int f = 0; f < 4; ++f) {
            short8 bf = *(const short8*)&W1[(size_t)(ct * 16 + cl) * DDIM + f * 32 + kg];
            acc = __builtin_amdgcn_mfma_f32_16x16x32_bf16(af[f], bf, acc, 0, 0, 0);
        }
        const float bv = b1[ct * 16 + cl];
#pragma unroll
        for (int j = 0; j < 4; ++j)
            hid[w][(rg + j) * 280 + ct * 16 + cl] = __float2bfloat16(fmaxf(acc[j] + bv, 0.f));
    }
    __syncthreads();

    short8 af2[8];
#pragma unroll
    for (int f = 0; f < 8; ++f)
        af2[f] = *(const short8*)&hid[w][cl * 280 + f * 32 + kg];

#pragma unroll
    for (int ct = 0; ct < 8; ++ct) {
        f32x4 acc = {0.f, 0.f, 0.f, 0.f};
#pragma unroll
        for (int f = 0; f < 8; ++f) {
            short8 bf = *(const short8*)&W2[(size_t)(ct * 16 + cl) * 256 + f * 32 + kg];
            acc = __builtin_amdgcn_mfma_f32_16x16x32_bf16(af2[f], bf, acc, 0, 0, 0);
        }
        const int c = ct * 16 + cl;
        const float bv = b2[c];
#pragma unroll
        for (int j = 0; j < 4; ++j) {
            const int r = row0 + rg + j;
            float v = acc[j] + bv + __bfloat162float(A[(size_t)r * DDIM + c]);
            v = bng[c] * v * bn_rsq() + bnb[c];
            out[(size_t)r * DDIM + c] = v;
        }
    }
}

// ---------------- fused attention per (graph, head) ----------------
__global__ __launch_bounds__(256) void k_attn(const __hip_bfloat16* __restrict__ qkv,
                                              __hip_bfloat16* __restrict__ o)
{
    const int g = blockIdx.x, h = blockIdx.y;
    __shared__ __align__(16) __hip_bfloat16 Kl[NPGD * 24];
    __shared__ __align__(16) __hip_bfloat16 Vt[16 * 200];
    __shared__ __align__(16) __hip_bfloat16 Pl[4][16 * 200];
    const int tid = threadIdx.x;
    const size_t gbase = (size_t)g * NPGD * 384;

    for (int i = tid; i < 384; i += 256) {
        int r = i >> 1, hf = i & 1;
        *(uint4*)&Kl[r * 24 + hf * 8] =
            *(const uint4*)&qkv[gbase + (size_t)r * 384 + 128 + h * 16 + hf * 8];
    }
    for (int i = tid; i < 3072; i += 256) {
        int k = i >> 4, d = i & 15;
        Vt[d * 200 + k] = qkv[gbase + (size_t)k * 384 + 256 + h * 16 + d];
    }
    __syncthreads();

    const int w = tid >> 6, l = tid & 63;
    const int cl = l & 15, gq = l >> 4;

    for (int it = 0; it < 3; ++it) {
        const int qt = w + it * 4;
        short8 aq = {0, 0, 0, 0, 0, 0, 0, 0};
        if (gq < 2)
            aq = *(const short8*)&qkv[gbase + (size_t)(qt * 16 + cl) * 384 + h * 16 + gq * 8];

        f32x4 s[12];
#pragma unroll
        for (int kt = 0; kt < 12; ++kt) {
            short8 bk = {0, 0, 0, 0, 0, 0, 0, 0};
            if (gq < 2)
                bk = *(const short8*)&Kl[(kt * 16 + cl) * 24 + gq * 8];
            f32x4 zz = {0.f, 0.f, 0.f, 0.f};
            s[kt] = __builtin_amdgcn_mfma_f32_16x16x32_bf16(aq, bk, zz, 0, 0, 0);
        }
#pragma unroll
        for (int kt = 0; kt < 12; ++kt) s[kt] *= 0.25f;

        float mj[4], sj[4];
#pragma unroll
        for (int j = 0; j < 4; ++j) {
            float mm = -3.0e38f;
#pragma unroll
            for (int kt = 0; kt < 12; ++kt) mm = fmaxf(mm, s[kt][j]);
            mm = fmaxf(mm, __shfl_xor(mm, 1));
            mm = fmaxf(mm, __shfl_xor(mm, 2));
            mm = fmaxf(mm, __shfl_xor(mm, 4));
            mm = fmaxf(mm, __shfl_xor(mm, 8));
            mj[j] = mm;
        }
#pragma unroll
        for (int j = 0; j < 4; ++j) {
            float sum = 0.f;
#pragma unroll
            for (int kt = 0; kt < 12; ++kt) {
                float p = __expf(s[kt][j] - mj[j]);
                s[kt][j] = p;
                sum += p;
            }
            sum += __shfl_xor(sum, 1);
            sum += __shfl_xor(sum, 2);
            sum += __shfl_xor(sum, 4);
            sum += __shfl_xor(sum, 8);
            sj[j] = 1.f / sum;
        }
#pragma unroll
        for (int kt = 0; kt < 12; ++kt)
#pragma unroll
            for (int j = 0; j < 4; ++j)
                Pl[w][(gq * 4 + j) * 200 + kt * 16 + cl] = __float2bfloat16(s[kt][j] * sj[j]);
        __syncthreads();

        f32x4 oa = {0.f, 0.f, 0.f, 0.f};
#pragma unroll
        for (int kt = 0; kt < 6; ++kt) {
            short8 ap = *(const short8*)&Pl[w][cl * 200 + kt * 32 + gq * 8];
            short8 av = *(const short8*)&Vt[cl * 200 + kt * 32 + gq * 8];
            oa = __builtin_amdgcn_mfma_f32_16x16x32_bf16(ap, av, oa, 0, 0, 0);
        }
#pragma unroll
        for (int j = 0; j < 4; ++j)
            o[((size_t)g * NPGD + qt * 16 + gq * 4 + j) * DDIM + h * 16 + cl] = __float2bfloat16(oa[j]);
        __syncthreads();
    }
}

// ---------------- launch ----------------
extern "C" void kernel_launch(void* const* d_in, const int* in_sizes, int n_in,
                              void* d_out, int out_size, void* d_ws, size_t ws_size,
                              hipStream_t stream) {
    (void)in_sizes; (void)n_in; (void)out_size; (void)ws_size;
    const float* x    = (const float*)d_in[0];
    const float* ea   = (const float*)d_in[1];
    const int*   ei   = (const int*)d_in[2];
    const float* gw1  = (const float*)d_in[3];
    const float* gb1  = (const float*)d_in[4];
    const float* gw2  = (const float*)d_in[5];
    const float* gb2  = (const float*)d_in[6];
    const float* ipw  = (const float*)d_in[7];
    const float* ipb  = (const float*)d_in[8];
    const float* opw  = (const float*)d_in[9];
    const float* opb  = (const float*)d_in[10];
    const float* b1lg = (const float*)d_in[11];
    const float* b1lb = (const float*)d_in[12];
    const float* b1gg = (const float*)d_in[13];
    const float* b1gb = (const float*)d_in[14];
    const float* b2g  = (const float*)d_in[15];
    const float* b2b  = (const float*)d_in[16];
    const float* fw1  = (const float*)d_in[17];
    const float* fb1  = (const float*)d_in[18];
    const float* fw2  = (const float*)d_in[19];
    const float* fb2  = (const float*)d_in[20];

    char* ws = (char*)d_ws;
    size_t off = 0;
    auto alloc = [&](size_t b) -> char* {
        char* p = ws + off;
        off = (off + b + 255) & ~(size_t)255;
        return p;
    };
    int*  cnt  = (int*)alloc((NN + 1) * 4);
    int*  offp = (int*)alloc((NN + 1) * 4);
    int*  cur  = (int*)alloc((NN + 1) * 4);
    __hip_bfloat16* wbuf = (__hip_bfloat16*)alloc(163840 * 2);
    int2* ecsr = (int2*)alloc((size_t)EE * 8);
    __hip_bfloat16* xb  = (__hip_bfloat16*)alloc((size_t)NN * DDIM * 2);
    __hip_bfloat16* zb  = (__hip_bfloat16*)alloc((size_t)NN * DDIM * 2);
    __hip_bfloat16* g1  = (__hip_bfloat16*)alloc((size_t)NN * DDIM * 2);
    __hip_bfloat16* hl  = (__hip_bfloat16*)alloc((size_t)NN * DDIM * 2);
    __hip_bfloat16* qkv = (__hip_bfloat16*)alloc((size_t)NN * 384 * 2);

    __hip_bfloat16* w1b  = wbuf;
    __hip_bfloat16* w2b  = wbuf + 16384;
    __hip_bfloat16* ipwb = wbuf + 32768;
    __hip_bfloat16* opwb = wbuf + 81920;
    __hip_bfloat16* f1b  = wbuf + 98304;
    __hip_bfloat16* f2bw = wbuf + 131072;

    const int* srcI = ei;
    const int* dstI = ei + EE;

    hipMemsetAsync(cnt, 0, (NN + 1) * 4, stream);
    k_prep<<<3232, 256, 0, stream>>>(dstI, cnt, gw1, gw2, ipw, opw, fw1, fw2, wbuf);
    k_scan<<<1, 1024, 0, stream>>>(cnt, offp, cur);
    k_scatter<<<EE / 256, 256, 0, stream>>>(dstI, srcI, cur, ecsr);
    // INSTRUMENTED x6: pure kernel, repeats idempotent; measures k_aggr in top-5
    k_aggr<<<NN / 4, 256, 0, stream>>>(x, ea, offp, ecsr, zb, xb, 6);
    k_gin<<<NN / 64, 256, 0, stream>>>(zb, w1b, gb1, w2b, gb2, x, b1lg, b1lb, hl);
    k_gemm<128, 384, 2><<<NN / 64, 256, 0, stream>>>(xb, 128, ipwb, ipb, qkv, 384,
                                                     nullptr, nullptr, nullptr, nullptr);
    k_attn<<<dim3(GG, HH), 256, 0, stream>>>(qkv, g1);
    k_gemm<128, 128, 3><<<NN / 64, 256, 0, stream>>>(g1, 128, opwb, opb, zb, 128,
                                                     x, hl, b1gg, b1gb);
    k_ffn<<<NN / 64, 256, 0, stream>>>(zb, f1b, fb1, f2bw, fb2, b2g, b2b, (float*)d_out);
}

// Round 4
// 480.862 us; speedup vs baseline: 2.0872x; 2.0872x over previous
//
#include <hip/hip_runtime.h>
#include <hip/hip_bf16.h>

#define GG   256
#define NPGD 192
#define NN   (GG*NPGD)    // 49152 nodes
#define DDIM 128
#define EE   786432
#define HH   8

typedef __attribute__((ext_vector_type(8))) short short8;
typedef __attribute__((ext_vector_type(4))) float f32x4;

__device__ __forceinline__ float bn_rsq() { return 0.9999950000374996f; } // 1/sqrt(1+1e-5)

// ---------------- prep: histogram | weight cvt | xb = bf16(x) ----------------
__global__ __launch_bounds__(256) void k_prep(
    const int* __restrict__ dst, int* __restrict__ cnt,
    const float* __restrict__ gw1, const float* __restrict__ gw2,
    const float* __restrict__ ipw, const float* __restrict__ opw,
    const float* __restrict__ fw1, const float* __restrict__ fw2,
    __hip_bfloat16* __restrict__ wb,
    const float* __restrict__ x, __hip_bfloat16* __restrict__ xb)
{
    const int b = blockIdx.x;
    if (b < 3072) {                       // edge-dst histogram
        int e = b * 256 + threadIdx.x;
        atomicAdd(&cnt[dst[e]], 1);
        return;
    }
    if (b < 3232) {                       // weights f32 -> bf16
        int g = (b - 3072) * 1024 + threadIdx.x * 4;
        const float* s; int off;
        if      (g <  16384) { s = gw1; off = 0; }
        else if (g <  32768) { s = gw2; off = 16384; }
        else if (g <  81920) { s = ipw; off = 32768; }
        else if (g <  98304) { s = opw; off = 81920; }
        else if (g < 131072) { s = fw1; off = 98304; }
        else                 { s = fw2; off = 131072; }
        float4 f = *(const float4*)&s[g - off];
        wb[g]     = __float2bfloat16(f.x);
        wb[g + 1] = __float2bfloat16(f.y);
        wb[g + 2] = __float2bfloat16(f.z);
        wb[g + 3] = __float2bfloat16(f.w);
        return;
    }
    // xb = bf16(x)
    int i = (b - 3232) * 1024 + threadIdx.x * 4;
    float4 f = *(const float4*)&x[i];
    __hip_bfloat162 p0, p1;
    p0.x = __float2bfloat16(f.x); p0.y = __float2bfloat16(f.y);
    p1.x = __float2bfloat16(f.z); p1.y = __float2bfloat16(f.w);
    *(__hip_bfloat162*)&xb[i]     = p0;
    *(__hip_bfloat162*)&xb[i + 2] = p1;
}

// ---------------- exclusive prefix scan over 49152 counts (1 block) ----------------
__global__ __launch_bounds__(1024) void k_scan(const int* __restrict__ cnt,
                                               int* __restrict__ offp, int* __restrict__ cur) {
    __shared__ int part[1024];
    const int t = threadIdx.x;
    const int4* c4 = (const int4*)cnt;
    int4 v[12];
    int s = 0;
#pragma unroll
    for (int i = 0; i < 12; ++i) {
        v[i] = c4[t * 12 + i];
        s += v[i].x + v[i].y + v[i].z + v[i].w;
    }
    part[t] = s;
    __syncthreads();
    for (int d = 1; d < 1024; d <<= 1) {
        int u = (t >= d) ? part[t - d] : 0;
        __syncthreads();
        part[t] += u;
        __syncthreads();
    }
    int pre = (t == 0) ? 0 : part[t - 1];
    int4* o4 = (int4*)offp;
    int4* u4 = (int4*)cur;
#pragma unroll
    for (int i = 0; i < 12; ++i) {
        int4 a = v[i], o;
        o.x = pre; pre += a.x;
        o.y = pre; pre += a.y;
        o.z = pre; pre += a.z;
        o.w = pre; pre += a.w;
        o4[t * 12 + i] = o;
        u4[t * 12 + i] = o;
    }
    if (t == 1023) offp[NN] = pre;
}

// ---------------- scatter: CSR payload {edge_id, src} ----------------
__global__ __launch_bounds__(256) void k_scatter(const int* __restrict__ dst, const int* __restrict__ src,
                                                 int* __restrict__ cur, int2* __restrict__ ecsr) {
    int e = blockIdx.x * 256 + threadIdx.x;
    int p = atomicAdd(&cur[dst[e]], 1);
    ecsr[p] = make_int2(e, src[e]);
}

// ---------------- fused1: GINE aggregate (blocks 0..12287) | in_proj GEMM (12288..13055) ----------------
__global__ __launch_bounds__(256) void k_fused1(
    const float* __restrict__ x, const float* __restrict__ ea,
    const int* __restrict__ offp, const int2* __restrict__ ecsr,
    __hip_bfloat16* __restrict__ z,
    const __hip_bfloat16* __restrict__ xb,
    const __hip_bfloat16* __restrict__ ipw, const float* __restrict__ ipb,
    __hip_bfloat16* __restrict__ qkv)
{
    const int tid = threadIdx.x;
    if (blockIdx.x < 12288) {
        // ---- aggregation: z = x + sum_in relu(x[src]+e)
        const int w = tid >> 6, l = tid & 63;
        const int v = blockIdx.x * 4 + w;
        const int c = l * 2;
        const int b = offp[v], e = offp[v + 1];
        float ax = 0.f, ay = 0.f;
        int i = b;
        for (; i + 2 <= e; i += 2) {
            const int2 p0 = ecsr[i];
            const int2 p1 = ecsr[i + 1];
            const float2 a0 = *(const float2*)&ea[(size_t)p0.x * DDIM + c];
            const float2 x0 = *(const float2*)&x[(size_t)p0.y * DDIM + c];
            const float2 a1 = *(const float2*)&ea[(size_t)p1.x * DDIM + c];
            const float2 x1 = *(const float2*)&x[(size_t)p1.y * DDIM + c];
            ax += fmaxf(a0.x + x0.x, 0.f) + fmaxf(a1.x + x1.x, 0.f);
            ay += fmaxf(a0.y + x0.y, 0.f) + fmaxf(a1.y + x1.y, 0.f);
        }
        if (i < e) {
            const int2 p0 = ecsr[i];
            const float2 a0 = *(const float2*)&ea[(size_t)p0.x * DDIM + c];
            const float2 x0 = *(const float2*)&x[(size_t)p0.y * DDIM + c];
            ax += fmaxf(a0.x + x0.x, 0.f);
            ay += fmaxf(a0.y + x0.y, 0.f);
        }
        const float2 xv = *(const float2*)&x[(size_t)v * DDIM + c];
        __hip_bfloat162 zz;
        zz.x = __float2bfloat16(xv.x + ax); zz.y = __float2bfloat16(xv.y + ay);
        *(__hip_bfloat162*)&z[(size_t)v * DDIM + c] = zz;
        return;
    }
    // ---- in_proj: qkv = xb @ ipw^T + ipb   (768 blocks, OUTD=384)
    const int bid = blockIdx.x - 12288;
    const int l = tid & 63, w = tid >> 6;
    const int row0 = bid * 64 + w * 16;
    const int cl = l & 15;
    const int kg = (l >> 4) * 8;
    const int rg = (l >> 4) * 4;

    short8 af[4];
#pragma unroll
    for (int f = 0; f < 4; ++f)
        af[f] = *(const short8*)&xb[(size_t)(row0 + cl) * DDIM + f * 32 + kg];

#pragma unroll
    for (int ct = 0; ct < 24; ++ct) {
        f32x4 acc = {0.f, 0.f, 0.f, 0.f};
#pragma unroll
        for (int f = 0; f < 4; ++f) {
            short8 bf = *(const short8*)&ipw[(size_t)(ct * 16 + cl) * DDIM + f * 32 + kg];
            acc = __builtin_amdgcn_mfma_f32_16x16x32_bf16(af[f], bf, acc, 0, 0, 0);
        }
        const int c = ct * 16 + cl;
        const float bv = ipb[c];
#pragma unroll
        for (int j = 0; j < 4; ++j)
            qkv[(size_t)(row0 + rg + j) * 384 + c] = __float2bfloat16(acc[j] + bv);
    }
}

// ---------------- fused2: attention (blocks 0..2047) | GIN MLP (2048..2815) ----------------
__global__ __launch_bounds__(256) void k_fused2(
    const __hip_bfloat16* __restrict__ qkv, __hip_bfloat16* __restrict__ o,
    const __hip_bfloat16* __restrict__ zb,
    const __hip_bfloat16* __restrict__ W1, const float* __restrict__ b1,
    const __hip_bfloat16* __restrict__ W2, const float* __restrict__ b2,
    const float* __restrict__ xres,
    const float* __restrict__ bng, const float* __restrict__ bnb,
    __hip_bfloat16* __restrict__ hl)
{
    __shared__ __align__(16) char smem[41216];
    const int tid = threadIdx.x;
    const int l = tid & 63, w = tid >> 6;
    const int cl = l & 15;
    const int kg = (l >> 4) * 8;
    const int rg = (l >> 4) * 4;

    if (blockIdx.x < 2048) {
        // ---- attention for (g, h)
        const int g = blockIdx.x >> 3, h = blockIdx.x & 7;
        __hip_bfloat16* Kl = (__hip_bfloat16*)smem;            // 192*24*2  = 9216 B
        __hip_bfloat16* Vt = (__hip_bfloat16*)(smem + 9216);   // 16*200*2  = 6400 B
        __hip_bfloat16* Pl = (__hip_bfloat16*)(smem + 15616);  // 4*16*200*2= 25600 B
        const size_t gbase = (size_t)g * NPGD * 384;

        for (int i = tid; i < 384; i += 256) {
            int r = i >> 1, hf = i & 1;
            *(uint4*)&Kl[r * 24 + hf * 8] =
                *(const uint4*)&qkv[gbase + (size_t)r * 384 + 128 + h * 16 + hf * 8];
        }
        for (int i = tid; i < 3072; i += 256) {
            int k = i >> 4, d = i & 15;
            Vt[d * 200 + k] = qkv[gbase + (size_t)k * 384 + 256 + h * 16 + d];
        }
        __syncthreads();

        const int gq = l >> 4;
        for (int it = 0; it < 3; ++it) {
            const int qt = w + it * 4;
            short8 aq = {0, 0, 0, 0, 0, 0, 0, 0};
            if (gq < 2)
                aq = *(const short8*)&qkv[gbase + (size_t)(qt * 16 + cl) * 384 + h * 16 + gq * 8];

            f32x4 s[12];
#pragma unroll
            for (int kt = 0; kt < 12; ++kt) {
                short8 bk = {0, 0, 0, 0, 0, 0, 0, 0};
                if (gq < 2)
                    bk = *(const short8*)&Kl[(kt * 16 + cl) * 24 + gq * 8];
                f32x4 zz = {0.f, 0.f, 0.f, 0.f};
                s[kt] = __builtin_amdgcn_mfma_f32_16x16x32_bf16(aq, bk, zz, 0, 0, 0);
            }
#pragma unroll
            for (int kt = 0; kt < 12; ++kt) s[kt] *= 0.25f;

            float mj[4], sj[4];
#pragma unroll
            for (int j = 0; j < 4; ++j) {
                float mm = -3.0e38f;
#pragma unroll
                for (int kt = 0; kt < 12; ++kt) mm = fmaxf(mm, s[kt][j]);
                mm = fmaxf(mm, __shfl_xor(mm, 1));
                mm = fmaxf(mm, __shfl_xor(mm, 2));
                mm = fmaxf(mm, __shfl_xor(mm, 4));
                mm = fmaxf(mm, __shfl_xor(mm, 8));
                mj[j] = mm;
            }
#pragma unroll
            for (int j = 0; j < 4; ++j) {
                float sum = 0.f;
#pragma unroll
                for (int kt = 0; kt < 12; ++kt) {
                    float p = __expf(s[kt][j] - mj[j]);
                    s[kt][j] = p;
                    sum += p;
                }
                sum += __shfl_xor(sum, 1);
                sum += __shfl_xor(sum, 2);
                sum += __shfl_xor(sum, 4);
                sum += __shfl_xor(sum, 8);
                sj[j] = 1.f / sum;
            }
#pragma unroll
            for (int kt = 0; kt < 12; ++kt)
#pragma unroll
                for (int j = 0; j < 4; ++j)
                    Pl[w * 3200 + (gq * 4 + j) * 200 + kt * 16 + cl] = __float2bfloat16(s[kt][j] * sj[j]);
            __syncthreads();

            f32x4 oa = {0.f, 0.f, 0.f, 0.f};
#pragma unroll
            for (int kt = 0; kt < 6; ++kt) {
                short8 ap = *(const short8*)&Pl[w * 3200 + cl * 200 + kt * 32 + gq * 8];
                short8 av = *(const short8*)&Vt[cl * 200 + kt * 32 + gq * 8];
                oa = __builtin_amdgcn_mfma_f32_16x16x32_bf16(ap, av, oa, 0, 0, 0);
            }
#pragma unroll
            for (int j = 0; j < 4; ++j)
                o[((size_t)g * NPGD + qt * 16 + gq * 4 + j) * DDIM + h * 16 + cl] = __float2bfloat16(oa[j]);
            __syncthreads();
        }
        return;
    }

    // ---- GIN MLP: hl = bn1l(x + relu(zb@W1^T+b1)@W2^T + b2)
    const int bid = blockIdx.x - 2048;
    __hip_bfloat16* hid = (__hip_bfloat16*)smem;               // 4*16*152*2 = 19456 B
    const int row0 = bid * 64 + w * 16;

    short8 af[4];
#pragma unroll
    for (int f = 0; f < 4; ++f)
        af[f] = *(const short8*)&zb[(size_t)(row0 + cl) * DDIM + f * 32 + kg];

#pragma unroll
    for (int ct = 0; ct < 8; ++ct) {
        f32x4 acc = {0.f, 0.f, 0.f, 0.f};
#pragma unroll
        for (int f = 0; f < 4; ++f) {
            short8 bf = *(const short8*)&W1[(size_t)(ct * 16 + cl) * DDIM + f * 32 + kg];
            acc = __builtin_amdgcn_mfma_f32_16x16x32_bf16(af[f], bf, acc, 0, 0, 0);
        }
        const float bv = b1[ct * 16 + cl];
#pragma unroll
        for (int j = 0; j < 4; ++j)
            hid[w * 2432 + (rg + j) * 152 + ct * 16 + cl] = __float2bfloat16(fmaxf(acc[j] + bv, 0.f));
    }
    __syncthreads();

    short8 af2[4];
#pragma unroll
    for (int f = 0; f < 4; ++f)
        af2[f] = *(const short8*)&hid[w * 2432 + cl * 152 + f * 32 + kg];

#pragma unroll
    for (int ct = 0; ct < 8; ++ct) {
        f32x4 acc = {0.f, 0.f, 0.f, 0.f};
#pragma unroll
        for (int f = 0; f < 4; ++f) {
            short8 bf = *(const short8*)&W2[(size_t)(ct * 16 + cl) * DDIM + f * 32 + kg];
            acc = __builtin_amdgcn_mfma_f32_16x16x32_bf16(af2[f], bf, acc, 0, 0, 0);
        }
        const int c = ct * 16 + cl;
        const float bv = b2[c];
#pragma unroll
        for (int j = 0; j < 4; ++j) {
            const int r = row0 + rg + j;
            float v = acc[j] + bv + xres[(size_t)r * DDIM + c];
            v = bng[c] * v * bn_rsq() + bnb[c];
            hl[(size_t)r * DDIM + c] = __float2bfloat16(v);
        }
    }
}

// ---------------- tail: out_proj + bn1g + merge + FFN + bn2 -> d_out (fp32) ----------------
__global__ __launch_bounds__(256) void k_tail(
    const __hip_bfloat16* __restrict__ o,
    const __hip_bfloat16* __restrict__ opw, const float* __restrict__ opb,
    const float* __restrict__ x, const __hip_bfloat16* __restrict__ hl,
    const float* __restrict__ b1gg, const float* __restrict__ b1gb,
    const __hip_bfloat16* __restrict__ fw1, const float* __restrict__ fb1,
    const __hip_bfloat16* __restrict__ fw2, const float* __restrict__ fb2,
    const float* __restrict__ b2g, const float* __restrict__ b2b,
    float* __restrict__ out)
{
    __shared__ __align__(16) __hip_bfloat16 hbuf[4][16 * 136];  // h tile (bf16)
    __shared__ __align__(16) __hip_bfloat16 hid[4][16 * 280];   // ffn hidden
    const int tid = threadIdx.x;
    const int l = tid & 63, w = tid >> 6;
    const int row0 = blockIdx.x * 64 + w * 16;
    const int cl = l & 15;
    const int kg = (l >> 4) * 8;
    const int rg = (l >> 4) * 4;

    // stage 1: h = bn1g(x + o@opw^T + opb) + hl   (kept fp32 in hreg)
    short8 af[4];
#pragma unroll
    for (int f = 0; f < 4; ++f)
        af[f] = *(const short8*)&o[(size_t)(row0 + cl) * DDIM + f * 32 + kg];

    float hreg[32];
#pragma unroll
    for (int ct = 0; ct < 8; ++ct) {
        f32x4 acc = {0.f, 0.f, 0.f, 0.f};
#pragma unroll
        for (int f = 0; f < 4; ++f) {
            short8 bf = *(const short8*)&opw[(size_t)(ct * 16 + cl) * DDIM + f * 32 + kg];
            acc = __builtin_amdgcn_mfma_f32_16x16x32_bf16(af[f], bf, acc, 0, 0, 0);
        }
        const int c = ct * 16 + cl;
        const float bv = opb[c];
#pragma unroll
        for (int j = 0; j < 4; ++j) {
            const int r = row0 + rg + j;
            float v = acc[j] + bv + x[(size_t)r * DDIM + c];
            v = b1gg[c] * v * bn_rsq() + b1gb[c];
            v += __bfloat162float(hl[(size_t)r * DDIM + c]);
            hreg[ct * 4 + j] = v;
            hbuf[w][(rg + j) * 136 + c] = __float2bfloat16(v);
        }
    }
    __syncthreads();

    // stage 2: hid = relu(h @ fw1^T + fb1)
    short8 af2[4];
#pragma unroll
    for (int f = 0; f < 4; ++f)
        af2[f] = *(const short8*)&hbuf[w][cl * 136 + f * 32 + kg];

#pragma unroll
    for (int ct = 0; ct < 16; ++ct) {
        f32x4 acc = {0.f, 0.f, 0.f, 0.f};
#pragma unroll
        for (int f = 0; f < 4; ++f) {
            short8 bf = *(const short8*)&fw1[(size_t)(ct * 16 + cl) * DDIM + f * 32 + kg];
            acc = __builtin_amdgcn_mfma_f32_16x16x32_bf16(af2[f], bf, acc, 0, 0, 0);
        }
        const float bv = fb1[ct * 16 + cl];
#pragma unroll
        for (int j = 0; j < 4; ++j)
            hid[w][(rg + j) * 280 + ct * 16 + cl] = __float2bfloat16(fmaxf(acc[j] + bv, 0.f));
    }
    __syncthreads();

    // stage 3: out = bn2(h + hid @ fw2^T + fb2)
    short8 af3[8];
#pragma unroll
    for (int f = 0; f < 8; ++f)
        af3[f] = *(const short8*)&hid[w][cl * 280 + f * 32 + kg];

#pragma unroll
    for (int ct = 0; ct < 8; ++ct) {
        f32x4 acc = {0.f, 0.f, 0.f, 0.f};
#pragma unroll
        for (int f = 0; f < 8; ++f) {
            short8 bf = *(const short8*)&fw2[(size_t)(ct * 16 + cl) * 256 + f * 32 + kg];
            acc = __builtin_amdgcn_mfma_f32_16x16x32_bf16(af3[f], bf, acc, 0, 0, 0);
        }
        const int c = ct * 16 + cl;
        const float bv = fb2[c];
#pragma unroll
        for (int j = 0; j < 4; ++j) {
            const int r = row0 + rg + j;
            float v = acc[j] + bv + hreg[ct * 4 + j];
            v = b2g[c] * v * bn_rsq() + b2b[c];
            out[(size_t)r * DDIM + c] = v;
        }
    }
}

// ---------------- launch ----------------
extern "C" void kernel_launch(void* const* d_in, const int* in_sizes, int n_in,
                              void* d_out, int out_size, void* d_ws, size_t ws_size,
                              hipStream_t stream) {
    (void)in_sizes; (void)n_in; (void)out_size; (void)ws_size;
    const float* x    = (const float*)d_in[0];
    const float* ea   = (const float*)d_in[1];
    const int*   ei   = (const int*)d_in[2];
    const float* gw1  = (const float*)d_in[3];
    const float* gb1  = (const float*)d_in[4];
    const float* gw2  = (const float*)d_in[5];
    const float* gb2  = (const float*)d_in[6];
    const float* ipw  = (const float*)d_in[7];
    const float* ipb  = (const float*)d_in[8];
    const float* opw  = (const float*)d_in[9];
    const float* opb  = (const float*)d_in[10];
    const float* b1lg = (const float*)d_in[11];
    const float* b1lb = (const float*)d_in[12];
    const float* b1gg = (const float*)d_in[13];
    const float* b1gb = (const float*)d_in[14];
    const float* b2g  = (const float*)d_in[15];
    const float* b2b  = (const float*)d_in[16];
    const float* fw1  = (const float*)d_in[17];
    const float* fb1  = (const float*)d_in[18];
    const float* fw2  = (const float*)d_in[19];
    const float* fb2  = (const float*)d_in[20];

    char* ws = (char*)d_ws;
    size_t off = 0;
    auto alloc = [&](size_t b) -> char* {
        char* p = ws + off;
        off = (off + b + 255) & ~(size_t)255;
        return p;
    };
    int*  cnt  = (int*)alloc((NN + 1) * 4);
    int*  offp = (int*)alloc((NN + 1) * 4);
    int*  cur  = (int*)alloc((NN + 1) * 4);
    __hip_bfloat16* wbuf = (__hip_bfloat16*)alloc(163840 * 2);
    int2* ecsr = (int2*)alloc((size_t)EE * 8);
    __hip_bfloat16* xb  = (__hip_bfloat16*)alloc((size_t)NN * DDIM * 2);
    __hip_bfloat16* zb  = (__hip_bfloat16*)alloc((size_t)NN * DDIM * 2);
    __hip_bfloat16* g1  = (__hip_bfloat16*)alloc((size_t)NN * DDIM * 2);  // attn out
    __hip_bfloat16* hl  = (__hip_bfloat16*)alloc((size_t)NN * DDIM * 2);  // h_local
    __hip_bfloat16* qkv = (__hip_bfloat16*)alloc((size_t)NN * 384 * 2);

    __hip_bfloat16* w1b  = wbuf;
    __hip_bfloat16* w2b  = wbuf + 16384;
    __hip_bfloat16* ipwb = wbuf + 32768;
    __hip_bfloat16* opwb = wbuf + 81920;
    __hip_bfloat16* f1b  = wbuf + 98304;
    __hip_bfloat16* f2bw = wbuf + 131072;

    const int* srcI = ei;
    const int* dstI = ei + EE;

    hipMemsetAsync(cnt, 0, (NN + 1) * 4, stream);
    k_prep<<<9376, 256, 0, stream>>>(dstI, cnt, gw1, gw2, ipw, opw, fw1, fw2, wbuf, x, xb);
    k_scan<<<1, 1024, 0, stream>>>(cnt, offp, cur);
    k_scatter<<<EE / 256, 256, 0, stream>>>(dstI, srcI, cur, ecsr);
    // aggregation (BW-bound) with in_proj GEMM (compute) riding along
    k_fused1<<<12288 + 768, 256, 0, stream>>>(x, ea, offp, ecsr, zb, xb, ipwb, ipb, qkv);
    // attention || GIN MLP
    k_fused2<<<2048 + 768, 256, 0, stream>>>(qkv, g1, zb, w1b, gb1, w2b, gb2, x, b1lg, b1lb, hl);
    // out_proj + bn1g + merge + FFN + bn2
    k_tail<<<NN / 64, 256, 0, stream>>>(g1, opwb, opb, x, hl, b1gg, b1gb,
                                        f1b, fb1, f2bw, fb2, b2g, b2b, (float*)d_out);
}

// Round 5
// 444.798 us; speedup vs baseline: 2.2564x; 1.0811x over previous
//
#include <hip/hip_runtime.h>
#include <hip/hip_bf16.h>

#define GG   256
#define NPGD 192
#define NN   (GG*NPGD)    // 49152 nodes
#define DDIM 128
#define EE   786432
#define HH   8

typedef __attribute__((ext_vector_type(8))) short short8;
typedef __attribute__((ext_vector_type(4))) float f32x4;

__device__ __forceinline__ float bn_rsq() { return 0.9999950000374996f; } // 1/sqrt(1+1e-5)

// ---------------- prep: histogram (0..3071) | weight cvt (3072..3231) ----------------
__global__ __launch_bounds__(256) void k_prep(
    const int* __restrict__ dst, int* __restrict__ cnt,
    const float* __restrict__ gw1, const float* __restrict__ gw2,
    const float* __restrict__ ipw, const float* __restrict__ opw,
    const float* __restrict__ fw1, const float* __restrict__ fw2,
    __hip_bfloat16* __restrict__ wb)
{
    const int b = blockIdx.x;
    if (b < 3072) {
        int e = b * 256 + threadIdx.x;
        atomicAdd(&cnt[dst[e]], 1);
        return;
    }
    int g = (b - 3072) * 1024 + threadIdx.x * 4;
    const float* s; int off;
    if      (g <  16384) { s = gw1; off = 0; }
    else if (g <  32768) { s = gw2; off = 16384; }
    else if (g <  81920) { s = ipw; off = 32768; }
    else if (g <  98304) { s = opw; off = 81920; }
    else if (g < 131072) { s = fw1; off = 98304; }
    else                 { s = fw2; off = 131072; }
    float4 f = *(const float4*)&s[g - off];
    wb[g]     = __float2bfloat16(f.x);
    wb[g + 1] = __float2bfloat16(f.y);
    wb[g + 2] = __float2bfloat16(f.z);
    wb[g + 3] = __float2bfloat16(f.w);
}

// ---------------- exclusive prefix scan over 49152 counts (1 block) ----------------
__global__ __launch_bounds__(1024) void k_scan(const int* __restrict__ cnt,
                                               int* __restrict__ offp, int* __restrict__ cur) {
    __shared__ int part[1024];
    const int t = threadIdx.x;
    const int4* c4 = (const int4*)cnt;
    int4 v[12];
    int s = 0;
#pragma unroll
    for (int i = 0; i < 12; ++i) {
        v[i] = c4[t * 12 + i];
        s += v[i].x + v[i].y + v[i].z + v[i].w;
    }
    part[t] = s;
    __syncthreads();
    for (int d = 1; d < 1024; d <<= 1) {
        int u = (t >= d) ? part[t - d] : 0;
        __syncthreads();
        part[t] += u;
        __syncthreads();
    }
    int pre = (t == 0) ? 0 : part[t - 1];
    int4* o4 = (int4*)offp;
    int4* u4 = (int4*)cur;
#pragma unroll
    for (int i = 0; i < 12; ++i) {
        int4 a = v[i], o;
        o.x = pre; pre += a.x;
        o.y = pre; pre += a.y;
        o.z = pre; pre += a.z;
        o.w = pre; pre += a.w;
        o4[t * 12 + i] = o;
        u4[t * 12 + i] = o;
    }
    if (t == 1023) offp[NN] = pre;
}

// ---------------- scatter: CSR payload {edge_id, src} ----------------
__global__ __launch_bounds__(256) void k_scatter(const int* __restrict__ dst, const int* __restrict__ src,
                                                 int* __restrict__ cur, int2* __restrict__ ecsr) {
    int e = blockIdx.x * 256 + threadIdx.x;
    int p = atomicAdd(&cur[dst[e]], 1);
    ecsr[p] = make_int2(e, src[e]);
}

// ---------------- GINE aggregate: z = x + sum_in relu(x[src]+e); xb = bf16(x) ----------------
// half-wave per edge: 32 lanes x float4 (16B) per edge row; 2 edges/wave/iter, unrolled x2.
__global__ __launch_bounds__(256) void k_aggr(
    const float* __restrict__ x, const float* __restrict__ ea,
    const int* __restrict__ offp, const int2* __restrict__ ecsr,
    __hip_bfloat16* __restrict__ z, __hip_bfloat16* __restrict__ xb)
{
    const int tid = threadIdx.x;
    const int w = tid >> 6;
    const int v = blockIdx.x * 4 + w;
    const int half = (tid >> 5) & 1;
    const int c = (tid & 31) * 4;
    const int b = offp[v], e = offp[v + 1];

    float ax = 0.f, ay = 0.f, az = 0.f, aw = 0.f;
    int i = b + half;
    for (; i + 2 < e; i += 4) {
        const int2 p0 = ecsr[i];
        const int2 p1 = ecsr[i + 2];
        const float4 a0 = *(const float4*)&ea[(size_t)p0.x * DDIM + c];
        const float4 x0 = *(const float4*)&x[(size_t)p0.y * DDIM + c];
        const float4 a1 = *(const float4*)&ea[(size_t)p1.x * DDIM + c];
        const float4 x1 = *(const float4*)&x[(size_t)p1.y * DDIM + c];
        ax += fmaxf(a0.x + x0.x, 0.f) + fmaxf(a1.x + x1.x, 0.f);
        ay += fmaxf(a0.y + x0.y, 0.f) + fmaxf(a1.y + x1.y, 0.f);
        az += fmaxf(a0.z + x0.z, 0.f) + fmaxf(a1.z + x1.z, 0.f);
        aw += fmaxf(a0.w + x0.w, 0.f) + fmaxf(a1.w + x1.w, 0.f);
    }
    if (i < e) {
        const int2 p0 = ecsr[i];
        const float4 a0 = *(const float4*)&ea[(size_t)p0.x * DDIM + c];
        const float4 x0 = *(const float4*)&x[(size_t)p0.y * DDIM + c];
        ax += fmaxf(a0.x + x0.x, 0.f);
        ay += fmaxf(a0.y + x0.y, 0.f);
        az += fmaxf(a0.z + x0.z, 0.f);
        aw += fmaxf(a0.w + x0.w, 0.f);
    }
    // combine the two halves (they hold the same channels for different edge subsets)
    ax += __shfl_xor(ax, 32);
    ay += __shfl_xor(ay, 32);
    az += __shfl_xor(az, 32);
    aw += __shfl_xor(aw, 32);

    const float4 xv = *(const float4*)&x[(size_t)v * DDIM + c];
    if (half == 0) {
        __hip_bfloat162 z0, z1;
        z0.x = __float2bfloat16(xv.x + ax); z0.y = __float2bfloat16(xv.y + ay);
        z1.x = __float2bfloat16(xv.z + az); z1.y = __float2bfloat16(xv.w + aw);
        *(__hip_bfloat162*)&z[(size_t)v * DDIM + c]     = z0;
        *(__hip_bfloat162*)&z[(size_t)v * DDIM + c + 2] = z1;
    } else {
        __hip_bfloat162 x0, x1;
        x0.x = __float2bfloat16(xv.x); x0.y = __float2bfloat16(xv.y);
        x1.x = __float2bfloat16(xv.z); x1.y = __float2bfloat16(xv.w);
        *(__hip_bfloat162*)&xb[(size_t)v * DDIM + c]     = x0;
        *(__hip_bfloat162*)&xb[(size_t)v * DDIM + c + 2] = x1;
    }
}

// ---------------- bf16 MFMA GEMM (weights from L2): out = A @ W^T + b -> bf16 ----------------
template<int K, int OUTD>
__global__ __launch_bounds__(256) void k_gemm(
    const __hip_bfloat16* __restrict__ A, int lda,
    const __hip_bfloat16* __restrict__ W,
    const float* __restrict__ bias,
    __hip_bfloat16* __restrict__ out, int ldo)
{
    const int tid = threadIdx.x;
    const int l = tid & 63, w = tid >> 6;
    const int row0 = blockIdx.x * 64 + w * 16;
    const int cl = l & 15;
    const int kg = (l >> 4) * 8;
    const int rg = (l >> 4) * 4;

    short8 af[K / 32];
#pragma unroll
    for (int f = 0; f < K / 32; ++f)
        af[f] = *(const short8*)&A[(size_t)(row0 + cl) * lda + f * 32 + kg];

#pragma unroll
    for (int ct = 0; ct < OUTD / 16; ++ct) {
        f32x4 acc = {0.f, 0.f, 0.f, 0.f};
#pragma unroll
        for (int f = 0; f < K / 32; ++f) {
            short8 bf = *(const short8*)&W[(size_t)(ct * 16 + cl) * K + f * 32 + kg];
            acc = __builtin_amdgcn_mfma_f32_16x16x32_bf16(af[f], bf, acc, 0, 0, 0);
        }
        const int c = ct * 16 + cl;
        const float bv = bias[c];
#pragma unroll
        for (int j = 0; j < 4; ++j)
            out[(size_t)(row0 + rg + j) * ldo + c] = __float2bfloat16(acc[j] + bv);
    }
}

// ---------------- fused2: attention (blocks 0..2047) | GIN MLP (2048..2815) ----------------
__global__ __launch_bounds__(256) void k_fused2(
    const __hip_bfloat16* __restrict__ qkv, __hip_bfloat16* __restrict__ o,
    const __hip_bfloat16* __restrict__ zb,
    const __hip_bfloat16* __restrict__ W1, const float* __restrict__ b1,
    const __hip_bfloat16* __restrict__ W2, const float* __restrict__ b2,
    const float* __restrict__ xres,
    const float* __restrict__ bng, const float* __restrict__ bnb,
    __hip_bfloat16* __restrict__ hl)
{
    __shared__ __align__(16) char smem[41216];
    const int tid = threadIdx.x;
    const int l = tid & 63, w = tid >> 6;
    const int cl = l & 15;
    const int kg = (l >> 4) * 8;
    const int rg = (l >> 4) * 4;

    if (blockIdx.x < 2048) {
        // ---- attention for (g, h)
        const int g = blockIdx.x >> 3, h = blockIdx.x & 7;
        __hip_bfloat16* Kl = (__hip_bfloat16*)smem;            // 192*24*2  = 9216 B
        __hip_bfloat16* Vt = (__hip_bfloat16*)(smem + 9216);   // 16*200*2  = 6400 B
        __hip_bfloat16* Pl = (__hip_bfloat16*)(smem + 15616);  // 4*16*200*2= 25600 B
        const size_t gbase = (size_t)g * NPGD * 384;

        for (int i = tid; i < 384; i += 256) {
            int r = i >> 1, hf = i & 1;
            *(uint4*)&Kl[r * 24 + hf * 8] =
                *(const uint4*)&qkv[gbase + (size_t)r * 384 + 128 + h * 16 + hf * 8];
        }
        for (int i = tid; i < 3072; i += 256) {
            int k = i >> 4, d = i & 15;
            Vt[d * 200 + k] = qkv[gbase + (size_t)k * 384 + 256 + h * 16 + d];
        }
        __syncthreads();

        const int gq = l >> 4;
        for (int it = 0; it < 3; ++it) {
            const int qt = w + it * 4;
            short8 aq = {0, 0, 0, 0, 0, 0, 0, 0};
            if (gq < 2)
                aq = *(const short8*)&qkv[gbase + (size_t)(qt * 16 + cl) * 384 + h * 16 + gq * 8];

            f32x4 s[12];
#pragma unroll
            for (int kt = 0; kt < 12; ++kt) {
                short8 bk = {0, 0, 0, 0, 0, 0, 0, 0};
                if (gq < 2)
                    bk = *(const short8*)&Kl[(kt * 16 + cl) * 24 + gq * 8];
                f32x4 zz = {0.f, 0.f, 0.f, 0.f};
                s[kt] = __builtin_amdgcn_mfma_f32_16x16x32_bf16(aq, bk, zz, 0, 0, 0);
            }
#pragma unroll
            for (int kt = 0; kt < 12; ++kt) s[kt] *= 0.25f;

            float mj[4], sj[4];
#pragma unroll
            for (int j = 0; j < 4; ++j) {
                float mm = -3.0e38f;
#pragma unroll
                for (int kt = 0; kt < 12; ++kt) mm = fmaxf(mm, s[kt][j]);
                mm = fmaxf(mm, __shfl_xor(mm, 1));
                mm = fmaxf(mm, __shfl_xor(mm, 2));
                mm = fmaxf(mm, __shfl_xor(mm, 4));
                mm = fmaxf(mm, __shfl_xor(mm, 8));
                mj[j] = mm;
            }
#pragma unroll
            for (int j = 0; j < 4; ++j) {
                float sum = 0.f;
#pragma unroll
                for (int kt = 0; kt < 12; ++kt) {
                    float p = __expf(s[kt][j] - mj[j]);
                    s[kt][j] = p;
                    sum += p;
                }
                sum += __shfl_xor(sum, 1);
                sum += __shfl_xor(sum, 2);
                sum += __shfl_xor(sum, 4);
                sum += __shfl_xor(sum, 8);
                sj[j] = 1.f / sum;
            }
#pragma unroll
            for (int kt = 0; kt < 12; ++kt)
#pragma unroll
                for (int j = 0; j < 4; ++j)
                    Pl[w * 3200 + (gq * 4 + j) * 200 + kt * 16 + cl] = __float2bfloat16(s[kt][j] * sj[j]);
            __syncthreads();

            f32x4 oa = {0.f, 0.f, 0.f, 0.f};
#pragma unroll
            for (int kt = 0; kt < 6; ++kt) {
                short8 ap = *(const short8*)&Pl[w * 3200 + cl * 200 + kt * 32 + gq * 8];
                short8 av = *(const short8*)&Vt[cl * 200 + kt * 32 + gq * 8];
                oa = __builtin_amdgcn_mfma_f32_16x16x32_bf16(ap, av, oa, 0, 0, 0);
            }
#pragma unroll
            for (int j = 0; j < 4; ++j)
                o[((size_t)g * NPGD + qt * 16 + gq * 4 + j) * DDIM + h * 16 + cl] = __float2bfloat16(oa[j]);
            __syncthreads();
        }
        return;
    }

    // ---- GIN MLP: hl = bn1l(x + relu(zb@W1^T+b1)@W2^T + b2)
    const int bid = blockIdx.x - 2048;
    __hip_bfloat16* hid = (__hip_bfloat16*)smem;               // 4*16*152*2 = 19456 B
    const int row0 = bid * 64 + w * 16;

    short8 af[4];
#pragma unroll
    for (int f = 0; f < 4; ++f)
        af[f] = *(const short8*)&zb[(size_t)(row0 + cl) * DDIM + f * 32 + kg];

#pragma unroll
    for (int ct = 0; ct < 8; ++ct) {
        f32x4 acc = {0.f, 0.f, 0.f, 0.f};
#pragma unroll
        for (int f = 0; f < 4; ++f) {
            short8 bf = *(const short8*)&W1[(size_t)(ct * 16 + cl) * DDIM + f * 32 + kg];
            acc = __builtin_amdgcn_mfma_f32_16x16x32_bf16(af[f], bf, acc, 0, 0, 0);
        }
        const float bv = b1[ct * 16 + cl];
#pragma unroll
        for (int j = 0; j < 4; ++j)
            hid[w * 2432 + (rg + j) * 152 + ct * 16 + cl] = __float2bfloat16(fmaxf(acc[j] + bv, 0.f));
    }
    __syncthreads();

    short8 af2[4];
#pragma unroll
    for (int f = 0; f < 4; ++f)
        af2[f] = *(const short8*)&hid[w * 2432 + cl * 152 + f * 32 + kg];

#pragma unroll
    for (int ct = 0; ct < 8; ++ct) {
        f32x4 acc = {0.f, 0.f, 0.f, 0.f};
#pragma unroll
        for (int f = 0; f < 4; ++f) {
            short8 bf = *(const short8*)&W2[(size_t)(ct * 16 + cl) * DDIM + f * 32 + kg];
            acc = __builtin_amdgcn_mfma_f32_16x16x32_bf16(af2[f], bf, acc, 0, 0, 0);
        }
        const int c = ct * 16 + cl;
        const float bv = b2[c];
#pragma unroll
        for (int j = 0; j < 4; ++j) {
            const int r = row0 + rg + j;
            float v = acc[j] + bv + xres[(size_t)r * DDIM + c];
            v = bng[c] * v * bn_rsq() + bnb[c];
            hl[(size_t)r * DDIM + c] = __float2bfloat16(v);
        }
    }
}

// ---------------- tail: out_proj + bn1g + merge + FFN + bn2 -> d_out (fp32) ----------------
__global__ __launch_bounds__(256) void k_tail(
    const __hip_bfloat16* __restrict__ o,
    const __hip_bfloat16* __restrict__ opw, const float* __restrict__ opb,
    const float* __restrict__ x, const __hip_bfloat16* __restrict__ hl,
    const float* __restrict__ b1gg, const float* __restrict__ b1gb,
    const __hip_bfloat16* __restrict__ fw1, const float* __restrict__ fb1,
    const __hip_bfloat16* __restrict__ fw2, const float* __restrict__ fb2,
    const float* __restrict__ b2g, const float* __restrict__ b2b,
    float* __restrict__ out)
{
    __shared__ __align__(16) __hip_bfloat16 hbuf[4][16 * 136];  // h tile (bf16)
    __shared__ __align__(16) __hip_bfloat16 hid[4][16 * 280];   // ffn hidden
    const int tid = threadIdx.x;
    const int l = tid & 63, w = tid >> 6;
    const int row0 = blockIdx.x * 64 + w * 16;
    const int cl = l & 15;
    const int kg = (l >> 4) * 8;
    const int rg = (l >> 4) * 4;

    // stage 1: h = bn1g(x + o@opw^T + opb) + hl   (kept fp32 in hreg)
    short8 af[4];
#pragma unroll
    for (int f = 0; f < 4; ++f)
        af[f] = *(const short8*)&o[(size_t)(row0 + cl) * DDIM + f * 32 + kg];

    float hreg[32];
#pragma unroll
    for (int ct = 0; ct < 8; ++ct) {
        f32x4 acc = {0.f, 0.f, 0.f, 0.f};
#pragma unroll
        for (int f = 0; f < 4; ++f) {
            short8 bf = *(const short8*)&opw[(size_t)(ct * 16 + cl) * DDIM + f * 32 + kg];
            acc = __builtin_amdgcn_mfma_f32_16x16x32_bf16(af[f], bf, acc, 0, 0, 0);
        }
        const int c = ct * 16 + cl;
        const float bv = opb[c];
#pragma unroll
        for (int j = 0; j < 4; ++j) {
            const int r = row0 + rg + j;
            float v = acc[j] + bv + x[(size_t)r * DDIM + c];
            v = b1gg[c] * v * bn_rsq() + b1gb[c];
            v += __bfloat162float(hl[(size_t)r * DDIM + c]);
            hreg[ct * 4 + j] = v;
            hbuf[w][(rg + j) * 136 + c] = __float2bfloat16(v);
        }
    }
    __syncthreads();

    // stage 2: hid = relu(h @ fw1^T + fb1)
    short8 af2[4];
#pragma unroll
    for (int f = 0; f < 4; ++f)
        af2[f] = *(const short8*)&hbuf[w][cl * 136 + f * 32 + kg];

#pragma unroll
    for (int ct = 0; ct < 16; ++ct) {
        f32x4 acc = {0.f, 0.f, 0.f, 0.f};
#pragma unroll
        for (int f = 0; f < 4; ++f) {
            short8 bf = *(const short8*)&fw1[(size_t)(ct * 16 + cl) * DDIM + f * 32 + kg];
            acc = __builtin_amdgcn_mfma_f32_16x16x32_bf16(af2[f], bf, acc, 0, 0, 0);
        }
        const float bv = fb1[ct * 16 + cl];
#pragma unroll
        for (int j = 0; j < 4; ++j)
            hid[w][(rg + j) * 280 + ct * 16 + cl] = __float2bfloat16(fmaxf(acc[j] + bv, 0.f));
    }
    __syncthreads();

    // stage 3: out = bn2(h + hid @ fw2^T + fb2)
    short8 af3[8];
#pragma unroll
    for (int f = 0; f < 8; ++f)
        af3[f] = *(const short8*)&hid[w][cl * 280 + f * 32 + kg];

#pragma unroll
    for (int ct = 0; ct < 8; ++ct) {
        f32x4 acc = {0.f, 0.f, 0.f, 0.f};
#pragma unroll
        for (int f = 0; f < 8; ++f) {
            short8 bf = *(const short8*)&fw2[(size_t)(ct * 16 + cl) * 256 + f * 32 + kg];
            acc = __builtin_amdgcn_mfma_f32_16x16x32_bf16(af3[f], bf, acc, 0, 0, 0);
        }
        const int c = ct * 16 + cl;
        const float bv = fb2[c];
#pragma unroll
        for (int j = 0; j < 4; ++j) {
            const int r = row0 + rg + j;
            float v = acc[j] + bv + hreg[ct * 4 + j];
            v = b2g[c] * v * bn_rsq() + b2b[c];
            out[(size_t)r * DDIM + c] = v;
        }
    }
}

// ---------------- launch ----------------
extern "C" void kernel_launch(void* const* d_in, const int* in_sizes, int n_in,
                              void* d_out, int out_size, void* d_ws, size_t ws_size,
                              hipStream_t stream) {
    (void)in_sizes; (void)n_in; (void)out_size; (void)ws_size;
    const float* x    = (const float*)d_in[0];
    const float* ea   = (const float*)d_in[1];
    const int*   ei   = (const int*)d_in[2];
    const float* gw1  = (const float*)d_in[3];
    const float* gb1  = (const float*)d_in[4];
    const float* gw2  = (const float*)d_in[5];
    const float* gb2  = (const float*)d_in[6];
    const float* ipw  = (const float*)d_in[7];
    const float* ipb  = (const float*)d_in[8];
    const float* opw  = (const float*)d_in[9];
    const float* opb  = (const float*)d_in[10];
    const float* b1lg = (const float*)d_in[11];
    const float* b1lb = (const float*)d_in[12];
    const float* b1gg = (const float*)d_in[13];
    const float* b1gb = (const float*)d_in[14];
    const float* b2g  = (const float*)d_in[15];
    const float* b2b  = (const float*)d_in[16];
    const float* fw1  = (const float*)d_in[17];
    const float* fb1  = (const float*)d_in[18];
    const float* fw2  = (const float*)d_in[19];
    const float* fb2  = (const float*)d_in[20];

    char* ws = (char*)d_ws;
    size_t off = 0;
    auto alloc = [&](size_t b) -> char* {
        char* p = ws + off;
        off = (off + b + 255) & ~(size_t)255;
        return p;
    };
    int*  cnt  = (int*)alloc((NN + 1) * 4);
    int*  offp = (int*)alloc((NN + 1) * 4);
    int*  cur  = (int*)alloc((NN + 1) * 4);
    __hip_bfloat16* wbuf = (__hip_bfloat16*)alloc(163840 * 2);
    int2* ecsr = (int2*)alloc((size_t)EE * 8);
    __hip_bfloat16* xb  = (__hip_bfloat16*)alloc((size_t)NN * DDIM * 2);
    __hip_bfloat16* zb  = (__hip_bfloat16*)alloc((size_t)NN * DDIM * 2);
    __hip_bfloat16* g1  = (__hip_bfloat16*)alloc((size_t)NN * DDIM * 2);  // attn out
    __hip_bfloat16* hl  = (__hip_bfloat16*)alloc((size_t)NN * DDIM * 2);  // h_local
    __hip_bfloat16* qkv = (__hip_bfloat16*)alloc((size_t)NN * 384 * 2);

    __hip_bfloat16* w1b  = wbuf;
    __hip_bfloat16* w2b  = wbuf + 16384;
    __hip_bfloat16* ipwb = wbuf + 32768;
    __hip_bfloat16* opwb = wbuf + 81920;
    __hip_bfloat16* f1b  = wbuf + 98304;
    __hip_bfloat16* f2bw = wbuf + 131072;

    const int* srcI = ei;
    const int* dstI = ei + EE;

    hipMemsetAsync(cnt, 0, (NN + 1) * 4, stream);
    k_prep<<<3232, 256, 0, stream>>>(dstI, cnt, gw1, gw2, ipw, opw, fw1, fw2, wbuf);
    k_scan<<<1, 1024, 0, stream>>>(cnt, offp, cur);
    k_scatter<<<EE / 256, 256, 0, stream>>>(dstI, srcI, cur, ecsr);
    // aggregation (low-VGPR, high-occupancy) -> zb, xb
    k_aggr<<<NN / 4, 256, 0, stream>>>(x, ea, offp, ecsr, zb, xb);
    // in_proj -> qkv
    k_gemm<128, 384><<<NN / 64, 256, 0, stream>>>(xb, 128, ipwb, ipb, qkv, 384);
    // attention || GIN MLP
    k_fused2<<<2048 + 768, 256, 0, stream>>>(qkv, g1, zb, w1b, gb1, w2b, gb2, x, b1lg, b1lb, hl);
    // out_proj + bn1g + merge + FFN + bn2
    k_tail<<<NN / 64, 256, 0, stream>>>(g1, opwb, opb, x, hl, b1gg, b1gb,
                                        f1b, fb1, f2bw, fb2, b2g, b2b, (float*)d_out);
}

// Round 6
// 377.019 us; speedup vs baseline: 2.6620x; 1.1798x over previous
//
#include <hip/hip_runtime.h>
#include <hip/hip_bf16.h>

#define GG   256
#define NPGD 192
#define NN   (GG*NPGD)    // 49152 nodes
#define DDIM 128
#define EE   786432
#define HH   8

typedef __attribute__((ext_vector_type(8))) short short8;
typedef __attribute__((ext_vector_type(4))) float f32x4;

__device__ __forceinline__ float bn_rsq() { return 0.9999950000374996f; } // 1/sqrt(1+1e-5)
__device__ __forceinline__ float bf2f(unsigned short u) { return __uint_as_float((unsigned)u << 16); }

// ---------------- prep: histogram (0..3071) | weight cvt (3072..3231) | xb=bf16(x) (3232..9375) ----------------
__global__ __launch_bounds__(256) void k_prep(
    const int* __restrict__ dst, int* __restrict__ cnt,
    const float* __restrict__ gw1, const float* __restrict__ gw2,
    const float* __restrict__ ipw, const float* __restrict__ opw,
    const float* __restrict__ fw1, const float* __restrict__ fw2,
    __hip_bfloat16* __restrict__ wb,
    const float* __restrict__ x, __hip_bfloat16* __restrict__ xb)
{
    const int b = blockIdx.x;
    if (b < 3072) {
        int e = b * 256 + threadIdx.x;
        atomicAdd(&cnt[dst[e]], 1);
        return;
    }
    if (b < 3232) {
        int g = (b - 3072) * 1024 + threadIdx.x * 4;
        const float* s; int off;
        if      (g <  16384) { s = gw1; off = 0; }
        else if (g <  32768) { s = gw2; off = 16384; }
        else if (g <  81920) { s = ipw; off = 32768; }
        else if (g <  98304) { s = opw; off = 81920; }
        else if (g < 131072) { s = fw1; off = 98304; }
        else                 { s = fw2; off = 131072; }
        float4 f = *(const float4*)&s[g - off];
        wb[g]     = __float2bfloat16(f.x);
        wb[g + 1] = __float2bfloat16(f.y);
        wb[g + 2] = __float2bfloat16(f.z);
        wb[g + 3] = __float2bfloat16(f.w);
        return;
    }
    int i = (b - 3232) * 1024 + threadIdx.x * 4;
    float4 f = *(const float4*)&x[i];
    ushort4 u;
    u.x = (unsigned short)(__bfloat16_as_ushort(__float2bfloat16(f.x)));
    u.y = (unsigned short)(__bfloat16_as_ushort(__float2bfloat16(f.y)));
    u.z = (unsigned short)(__bfloat16_as_ushort(__float2bfloat16(f.z)));
    u.w = (unsigned short)(__bfloat16_as_ushort(__float2bfloat16(f.w)));
    *(ushort4*)&xb[i] = u;
}

// ---------------- exclusive prefix scan over 49152 counts (1 block) ----------------
__global__ __launch_bounds__(1024) void k_scan(const int* __restrict__ cnt,
                                               int* __restrict__ offp, int* __restrict__ cur) {
    __shared__ int part[1024];
    const int t = threadIdx.x;
    const int4* c4 = (const int4*)cnt;
    int4 v[12];
    int s = 0;
#pragma unroll
    for (int i = 0; i < 12; ++i) {
        v[i] = c4[t * 12 + i];
        s += v[i].x + v[i].y + v[i].z + v[i].w;
    }
    part[t] = s;
    __syncthreads();
    for (int d = 1; d < 1024; d <<= 1) {
        int u = (t >= d) ? part[t - d] : 0;
        __syncthreads();
        part[t] += u;
        __syncthreads();
    }
    int pre = (t == 0) ? 0 : part[t - 1];
    int4* o4 = (int4*)offp;
    int4* u4 = (int4*)cur;
#pragma unroll
    for (int i = 0; i < 12; ++i) {
        int4 a = v[i], o;
        o.x = pre; pre += a.x;
        o.y = pre; pre += a.y;
        o.z = pre; pre += a.z;
        o.w = pre; pre += a.w;
        o4[t * 12 + i] = o;
        u4[t * 12 + i] = o;
    }
    if (t == 1023) offp[NN] = pre;
}

// ---------------- scatter: CSR payload {edge_id, src} ----------------
__global__ __launch_bounds__(256) void k_scatter(const int* __restrict__ dst, const int* __restrict__ src,
                                                 int* __restrict__ cur, int2* __restrict__ ecsr) {
    int e = blockIdx.x * 256 + threadIdx.x;
    int p = atomicAdd(&cur[dst[e]], 1);
    ecsr[p] = make_int2(e, src[e]);
}

// ---------------- GINE aggregate: z = x + sum_in relu(xb[src]+e) ----------------
// half-wave per edge row (32 lanes x float4/ushort4); contiguous half-split, unroll x4.
__global__ __launch_bounds__(256, 8) void k_aggr(
    const float* __restrict__ x, const __hip_bfloat16* __restrict__ xb,
    const float* __restrict__ ea,
    const int* __restrict__ offp, const int2* __restrict__ ecsr,
    __hip_bfloat16* __restrict__ z)
{
    const int tid = threadIdx.x;
    const int w = tid >> 6;
    const int v = blockIdx.x * 4 + w;
    const int half = (tid >> 5) & 1;
    const int c = (tid & 31) * 4;
    const int b = offp[v], e = offp[v + 1];
    const int n = e - b;
    const int nh = (n + 1) >> 1;
    const int s0 = b + (half ? nh : 0);
    const int end = half ? e : (b + nh);

    float ax = 0.f, ay = 0.f, az = 0.f, aw = 0.f;
    int i = s0;
    for (; i + 3 < end; i += 4) {
        const int2 p0 = ecsr[i];
        const int2 p1 = ecsr[i + 1];
        const int2 p2 = ecsr[i + 2];
        const int2 p3 = ecsr[i + 3];
        const float4  a0 = *(const float4*)&ea[(size_t)p0.x * DDIM + c];
        const ushort4 s0v = *(const ushort4*)&xb[(size_t)p0.y * DDIM + c];
        const float4  a1 = *(const float4*)&ea[(size_t)p1.x * DDIM + c];
        const ushort4 s1v = *(const ushort4*)&xb[(size_t)p1.y * DDIM + c];
        const float4  a2 = *(const float4*)&ea[(size_t)p2.x * DDIM + c];
        const ushort4 s2v = *(const ushort4*)&xb[(size_t)p2.y * DDIM + c];
        const float4  a3 = *(const float4*)&ea[(size_t)p3.x * DDIM + c];
        const ushort4 s3v = *(const ushort4*)&xb[(size_t)p3.y * DDIM + c];
        ax += fmaxf(a0.x + bf2f(s0v.x), 0.f) + fmaxf(a1.x + bf2f(s1v.x), 0.f)
            + fmaxf(a2.x + bf2f(s2v.x), 0.f) + fmaxf(a3.x + bf2f(s3v.x), 0.f);
        ay += fmaxf(a0.y + bf2f(s0v.y), 0.f) + fmaxf(a1.y + bf2f(s1v.y), 0.f)
            + fmaxf(a2.y + bf2f(s2v.y), 0.f) + fmaxf(a3.y + bf2f(s3v.y), 0.f);
        az += fmaxf(a0.z + bf2f(s0v.z), 0.f) + fmaxf(a1.z + bf2f(s1v.z), 0.f)
            + fmaxf(a2.z + bf2f(s2v.z), 0.f) + fmaxf(a3.z + bf2f(s3v.z), 0.f);
        aw += fmaxf(a0.w + bf2f(s0v.w), 0.f) + fmaxf(a1.w + bf2f(s1v.w), 0.f)
            + fmaxf(a2.w + bf2f(s2v.w), 0.f) + fmaxf(a3.w + bf2f(s3v.w), 0.f);
    }
    for (; i < end; ++i) {
        const int2 p0 = ecsr[i];
        const float4  a0 = *(const float4*)&ea[(size_t)p0.x * DDIM + c];
        const ushort4 s0v = *(const ushort4*)&xb[(size_t)p0.y * DDIM + c];
        ax += fmaxf(a0.x + bf2f(s0v.x), 0.f);
        ay += fmaxf(a0.y + bf2f(s0v.y), 0.f);
        az += fmaxf(a0.z + bf2f(s0v.z), 0.f);
        aw += fmaxf(a0.w + bf2f(s0v.w), 0.f);
    }
    ax += __shfl_xor(ax, 32);
    ay += __shfl_xor(ay, 32);
    az += __shfl_xor(az, 32);
    aw += __shfl_xor(aw, 32);

    if (half == 0) {
        const float4 xv = *(const float4*)&x[(size_t)v * DDIM + c];
        ushort4 u;
        u.x = __bfloat16_as_ushort(__float2bfloat16(xv.x + ax));
        u.y = __bfloat16_as_ushort(__float2bfloat16(xv.y + ay));
        u.z = __bfloat16_as_ushort(__float2bfloat16(xv.z + az));
        u.w = __bfloat16_as_ushort(__float2bfloat16(xv.w + aw));
        *(ushort4*)&z[(size_t)v * DDIM + c] = u;
    }
}

// ---------------- fused2: attention+in_proj (blocks 0..2047) | GIN MLP (2048..2815) ----------------
__global__ __launch_bounds__(256) void k_fused2(
    const __hip_bfloat16* __restrict__ xb,
    const __hip_bfloat16* __restrict__ ipw, const float* __restrict__ ipb,
    __hip_bfloat16* __restrict__ o,
    const __hip_bfloat16* __restrict__ zb,
    const __hip_bfloat16* __restrict__ W1, const float* __restrict__ b1,
    const __hip_bfloat16* __restrict__ W2, const float* __restrict__ b2,
    const float* __restrict__ xres,
    const float* __restrict__ bng, const float* __restrict__ bnb,
    __hip_bfloat16* __restrict__ hl)
{
    __shared__ __align__(16) char smem[50432];
    const int tid = threadIdx.x;
    const int l = tid & 63, w = tid >> 6;
    const int cl = l & 15;
    const int kg = (l >> 4) * 8;
    const int rg = (l >> 4) * 4;

    if (blockIdx.x < 2048) {
        // ---- attention for (g, h), in_proj fused (disjoint head slice)
        const int g = blockIdx.x >> 3, h = blockIdx.x & 7;
        __hip_bfloat16* Ql = (__hip_bfloat16*)smem;             // 192*24*2 = 9216 B
        __hip_bfloat16* Kl = (__hip_bfloat16*)(smem + 9216);    // 9216 B
        __hip_bfloat16* Vt = (__hip_bfloat16*)(smem + 18432);   // 16*200*2 = 6400 B
        __hip_bfloat16* Pl = (__hip_bfloat16*)(smem + 24832);   // 4*16*200*2 = 25600 B
        const __hip_bfloat16* xg = xb + (size_t)g * NPGD * DDIM;
        const int gq = l >> 4;

        // q/k/v slice for this head: [192 x 16] each; wave w owns row-tiles {w, w+4, w+8}
        const float biq = ipb[h * 16 + cl];
        const float bik = ipb[128 + h * 16 + cl];
        const float biv = ipb[256 + h * 16 + cl];
        for (int mt = w; mt < 12; mt += 4) {
            short8 afr[4];
#pragma unroll
            for (int f = 0; f < 4; ++f)
                afr[f] = *(const short8*)&xg[(size_t)(mt * 16 + cl) * DDIM + f * 32 + kg];
            f32x4 qa = {0.f, 0.f, 0.f, 0.f}, ka = {0.f, 0.f, 0.f, 0.f}, va = {0.f, 0.f, 0.f, 0.f};
#pragma unroll
            for (int f = 0; f < 4; ++f) {
                short8 bq = *(const short8*)&ipw[(size_t)(h * 16 + cl) * DDIM + f * 32 + kg];
                short8 bk = *(const short8*)&ipw[(size_t)(128 + h * 16 + cl) * DDIM + f * 32 + kg];
                short8 bv = *(const short8*)&ipw[(size_t)(256 + h * 16 + cl) * DDIM + f * 32 + kg];
                qa = __builtin_amdgcn_mfma_f32_16x16x32_bf16(afr[f], bq, qa, 0, 0, 0);
                ka = __builtin_amdgcn_mfma_f32_16x16x32_bf16(afr[f], bk, ka, 0, 0, 0);
                va = __builtin_amdgcn_mfma_f32_16x16x32_bf16(afr[f], bv, va, 0, 0, 0);
            }
#pragma unroll
            for (int j = 0; j < 4; ++j) {
                const int r = mt * 16 + rg + j;
                Ql[r * 24 + cl] = __float2bfloat16((qa[j] + biq) * 0.25f);  // 1/sqrt(dh) folded (exact)
                Kl[r * 24 + cl] = __float2bfloat16(ka[j] + bik);
                Vt[cl * 200 + r] = __float2bfloat16(va[j] + biv);
            }
        }
        __syncthreads();

        for (int it = 0; it < 3; ++it) {
            const int qt = w + it * 4;
            short8 aq = {0, 0, 0, 0, 0, 0, 0, 0};
            if (gq < 2)
                aq = *(const short8*)&Ql[(qt * 16 + cl) * 24 + gq * 8];

            f32x4 s[12];
#pragma unroll
            for (int kt = 0; kt < 12; ++kt) {
                short8 bk = {0, 0, 0, 0, 0, 0, 0, 0};
                if (gq < 2)
                    bk = *(const short8*)&Kl[(kt * 16 + cl) * 24 + gq * 8];
                f32x4 zz = {0.f, 0.f, 0.f, 0.f};
                s[kt] = __builtin_amdgcn_mfma_f32_16x16x32_bf16(aq, bk, zz, 0, 0, 0);
            }

            float mj[4], sj[4];
#pragma unroll
            for (int j = 0; j < 4; ++j) {
                float mm = -3.0e38f;
#pragma unroll
                for (int kt = 0; kt < 12; ++kt) mm = fmaxf(mm, s[kt][j]);
                mm = fmaxf(mm, __shfl_xor(mm, 1));
                mm = fmaxf(mm, __shfl_xor(mm, 2));
                mm = fmaxf(mm, __shfl_xor(mm, 4));
                mm = fmaxf(mm, __shfl_xor(mm, 8));
                mj[j] = mm;
            }
#pragma unroll
            for (int j = 0; j < 4; ++j) {
                float sum = 0.f;
#pragma unroll
                for (int kt = 0; kt < 12; ++kt) {
                    float p = __expf(s[kt][j] - mj[j]);
                    s[kt][j] = p;
                    sum += p;
                }
                sum += __shfl_xor(sum, 1);
                sum += __shfl_xor(sum, 2);
                sum += __shfl_xor(sum, 4);
                sum += __shfl_xor(sum, 8);
                sj[j] = 1.f / sum;
            }
#pragma unroll
            for (int kt = 0; kt < 12; ++kt)
#pragma unroll
                for (int j = 0; j < 4; ++j)
                    Pl[w * 3200 + (gq * 4 + j) * 200 + kt * 16 + cl] = __float2bfloat16(s[kt][j] * sj[j]);
            __syncthreads();

            f32x4 oa = {0.f, 0.f, 0.f, 0.f};
#pragma unroll
            for (int kt = 0; kt < 6; ++kt) {
                short8 ap = *(const short8*)&Pl[w * 3200 + cl * 200 + kt * 32 + gq * 8];
                short8 av = *(const short8*)&Vt[cl * 200 + kt * 32 + gq * 8];
                oa = __builtin_amdgcn_mfma_f32_16x16x32_bf16(ap, av, oa, 0, 0, 0);
            }
#pragma unroll
            for (int j = 0; j < 4; ++j)
                o[((size_t)g * NPGD + qt * 16 + gq * 4 + j) * DDIM + h * 16 + cl] = __float2bfloat16(oa[j]);
            __syncthreads();
        }
        return;
    }

    // ---- GIN MLP: hl = bn1l(x + relu(zb@W1^T+b1)@W2^T + b2)
    const int bid = blockIdx.x - 2048;
    __hip_bfloat16* hid = (__hip_bfloat16*)smem;               // 4*16*152*2 = 19456 B
    const int row0 = bid * 64 + w * 16;

    short8 af[4];
#pragma unroll
    for (int f = 0; f < 4; ++f)
        af[f] = *(const short8*)&zb[(size_t)(row0 + cl) * DDIM + f * 32 + kg];

#pragma unroll
    for (int ct = 0; ct < 8; ++ct) {
        f32x4 acc = {0.f, 0.f, 0.f, 0.f};
#pragma unroll
        for (int f = 0; f < 4; ++f) {
            short8 bf = *(const short8*)&W1[(size_t)(ct * 16 + cl) * DDIM + f * 32 + kg];
            acc = __builtin_amdgcn_mfma_f32_16x16x32_bf16(af[f], bf, acc, 0, 0, 0);
        }
        const float bv = b1[ct * 16 + cl];
#pragma unroll
        for (int j = 0; j < 4; ++j)
            hid[w * 2432 + (rg + j) * 152 + ct * 16 + cl] = __float2bfloat16(fmaxf(acc[j] + bv, 0.f));
    }
    __syncthreads();

    short8 af2[4];
#pragma unroll
    for (int f = 0; f < 4; ++f)
        af2[f] = *(const short8*)&hid[w * 2432 + cl * 152 + f * 32 + kg];

#pragma unroll
    for (int ct = 0; ct < 8; ++ct) {
        f32x4 acc = {0.f, 0.f, 0.f, 0.f};
#pragma unroll
        for (int f = 0; f < 4; ++f) {
            short8 bf = *(const short8*)&W2[(size_t)(ct * 16 + cl) * DDIM + f * 32 + kg];
            acc = __builtin_amdgcn_mfma_f32_16x16x32_bf16(af2[f], bf, acc, 0, 0, 0);
        }
        const int c = ct * 16 + cl;
        const float bv = b2[c];
#pragma unroll
        for (int j = 0; j < 4; ++j) {
            const int r = row0 + rg + j;
            float v = acc[j] + bv + xres[(size_t)r * DDIM + c];
            v = bng[c] * v * bn_rsq() + bnb[c];
            hl[(size_t)r * DDIM + c] = __float2bfloat16(v);
        }
    }
}

// ---------------- tail: out_proj + bn1g + merge + FFN + bn2 -> d_out (fp32) ----------------
__global__ __launch_bounds__(256) void k_tail(
    const __hip_bfloat16* __restrict__ o,
    const __hip_bfloat16* __restrict__ opw, const float* __restrict__ opb,
    const float* __restrict__ x, const __hip_bfloat16* __restrict__ hl,
    const float* __restrict__ b1gg, const float* __restrict__ b1gb,
    const __hip_bfloat16* __restrict__ fw1, const float* __restrict__ fb1,
    const __hip_bfloat16* __restrict__ fw2, const float* __restrict__ fb2,
    const float* __restrict__ b2g, const float* __restrict__ b2b,
    float* __restrict__ out)
{
    __shared__ __align__(16) __hip_bfloat16 hbuf[4][16 * 136];  // h tile (bf16)
    __shared__ __align__(16) __hip_bfloat16 hid[4][16 * 280];   // ffn hidden
    const int tid = threadIdx.x;
    const int l = tid & 63, w = tid >> 6;
    const int row0 = blockIdx.x * 64 + w * 16;
    const int cl = l & 15;
    const int kg = (l >> 4) * 8;
    const int rg = (l >> 4) * 4;

    // stage 1: h = bn1g(x + o@opw^T + opb) + hl   (kept fp32 in hreg)
    short8 af[4];
#pragma unroll
    for (int f = 0; f < 4; ++f)
        af[f] = *(const short8*)&o[(size_t)(row0 + cl) * DDIM + f * 32 + kg];

    float hreg[32];
#pragma unroll
    for (int ct = 0; ct < 8; ++ct) {
        f32x4 acc = {0.f, 0.f, 0.f, 0.f};
#pragma unroll
        for (int f = 0; f < 4; ++f) {
            short8 bf = *(const short8*)&opw[(size_t)(ct * 16 + cl) * DDIM + f * 32 + kg];
            acc = __builtin_amdgcn_mfma_f32_16x16x32_bf16(af[f], bf, acc, 0, 0, 0);
        }
        const int c = ct * 16 + cl;
        const float bv = opb[c];
#pragma unroll
        for (int j = 0; j < 4; ++j) {
            const int r = row0 + rg + j;
            float v = acc[j] + bv + x[(size_t)r * DDIM + c];
            v = b1gg[c] * v * bn_rsq() + b1gb[c];
            v += __bfloat162float(hl[(size_t)r * DDIM + c]);
            hreg[ct * 4 + j] = v;
            hbuf[w][(rg + j) * 136 + c] = __float2bfloat16(v);
        }
    }
    __syncthreads();

    // stage 2: hid = relu(h @ fw1^T + fb1)
    short8 af2[4];
#pragma unroll
    for (int f = 0; f < 4; ++f)
        af2[f] = *(const short8*)&hbuf[w][cl * 136 + f * 32 + kg];

#pragma unroll
    for (int ct = 0; ct < 16; ++ct) {
        f32x4 acc = {0.f, 0.f, 0.f, 0.f};
#pragma unroll
        for (int f = 0; f < 4; ++f) {
            short8 bf = *(const short8*)&fw1[(size_t)(ct * 16 + cl) * DDIM + f * 32 + kg];
            acc = __builtin_amdgcn_mfma_f32_16x16x32_bf16(af2[f], bf, acc, 0, 0, 0);
        }
        const float bv = fb1[ct * 16 + cl];
#pragma unroll
        for (int j = 0; j < 4; ++j)
            hid[w][(rg + j) * 280 + ct * 16 + cl] = __float2bfloat16(fmaxf(acc[j] + bv, 0.f));
    }
    __syncthreads();

    // stage 3: out = bn2(h + hid @ fw2^T + fb2)
    short8 af3[8];
#pragma unroll
    for (int f = 0; f < 8; ++f)
        af3[f] = *(const short8*)&hid[w][cl * 280 + f * 32 + kg];

#pragma unroll
    for (int ct = 0; ct < 8; ++ct) {
        f32x4 acc = {0.f, 0.f, 0.f, 0.f};
#pragma unroll
        for (int f = 0; f < 8; ++f) {
            short8 bf = *(const short8*)&fw2[(size_t)(ct * 16 + cl) * 256 + f * 32 + kg];
            acc = __builtin_amdgcn_mfma_f32_16x16x32_bf16(af3[f], bf, acc, 0, 0, 0);
        }
        const int c = ct * 16 + cl;
        const float bv = fb2[c];
#pragma unroll
        for (int j = 0; j < 4; ++j) {
            const int r = row0 + rg + j;
            float v = acc[j] + bv + hreg[ct * 4 + j];
            v = b2g[c] * v * bn_rsq() + b2b[c];
            out[(size_t)r * DDIM + c] = v;
        }
    }
}

// ---------------- launch ----------------
extern "C" void kernel_launch(void* const* d_in, const int* in_sizes, int n_in,
                              void* d_out, int out_size, void* d_ws, size_t ws_size,
                              hipStream_t stream) {
    (void)in_sizes; (void)n_in; (void)out_size; (void)ws_size;
    const float* x    = (const float*)d_in[0];
    const float* ea   = (const float*)d_in[1];
    const int*   ei   = (const int*)d_in[2];
    const float* gw1  = (const float*)d_in[3];
    const float* gb1  = (const float*)d_in[4];
    const float* gw2  = (const float*)d_in[5];
    const float* gb2  = (const float*)d_in[6];
    const float* ipw  = (const float*)d_in[7];
    const float* ipb  = (const float*)d_in[8];
    const float* opw  = (const float*)d_in[9];
    const float* opb  = (const float*)d_in[10];
    const float* b1lg = (const float*)d_in[11];
    const float* b1lb = (const float*)d_in[12];
    const float* b1gg = (const float*)d_in[13];
    const float* b1gb = (const float*)d_in[14];
    const float* b2g  = (const float*)d_in[15];
    const float* b2b  = (const float*)d_in[16];
    const float* fw1  = (const float*)d_in[17];
    const float* fb1  = (const float*)d_in[18];
    const float* fw2  = (const float*)d_in[19];
    const float* fb2  = (const float*)d_in[20];

    char* ws = (char*)d_ws;
    size_t off = 0;
    auto alloc = [&](size_t b) -> char* {
        char* p = ws + off;
        off = (off + b + 255) & ~(size_t)255;
        return p;
    };
    int*  cnt  = (int*)alloc((NN + 1) * 4);
    int*  offp = (int*)alloc((NN + 1) * 4);
    int*  cur  = (int*)alloc((NN + 1) * 4);
    __hip_bfloat16* wbuf = (__hip_bfloat16*)alloc(163840 * 2);
    int2* ecsr = (int2*)alloc((size_t)EE * 8);
    __hip_bfloat16* xb  = (__hip_bfloat16*)alloc((size_t)NN * DDIM * 2);
    __hip_bfloat16* zb  = (__hip_bfloat16*)alloc((size_t)NN * DDIM * 2);
    __hip_bfloat16* g1  = (__hip_bfloat16*)alloc((size_t)NN * DDIM * 2);  // attn out
    __hip_bfloat16* hl  = (__hip_bfloat16*)alloc((size_t)NN * DDIM * 2);  // h_local

    __hip_bfloat16* w1b  = wbuf;
    __hip_bfloat16* w2b  = wbuf + 16384;
    __hip_bfloat16* ipwb = wbuf + 32768;
    __hip_bfloat16* opwb = wbuf + 81920;
    __hip_bfloat16* f1b  = wbuf + 98304;
    __hip_bfloat16* f2bw = wbuf + 131072;

    const int* srcI = ei;
    const int* dstI = ei + EE;

    hipMemsetAsync(cnt, 0, (NN + 1) * 4, stream);
    k_prep<<<9376, 256, 0, stream>>>(dstI, cnt, gw1, gw2, ipw, opw, fw1, fw2, wbuf, x, xb);
    k_scan<<<1, 1024, 0, stream>>>(cnt, offp, cur);
    k_scatter<<<EE / 256, 256, 0, stream>>>(dstI, srcI, cur, ecsr);
    // aggregation (low-VGPR, high-occupancy; bf16 gather) -> zb
    k_aggr<<<NN / 4, 256, 0, stream>>>(x, xb, ea, offp, ecsr, zb);
    // attention (with fused in_proj) || GIN MLP
    k_fused2<<<2048 + 768, 256, 0, stream>>>(xb, ipwb, ipb, g1, zb, w1b, gb1, w2b, gb2,
                                             x, b1lg, b1lb, hl);
    // out_proj + bn1g + merge + FFN + bn2
    k_tail<<<NN / 64, 256, 0, stream>>>(g1, opwb, opb, x, hl, b1gg, b1gb,
                                        f1b, fb1, f2bw, fb2, b2g, b2b, (float*)d_out);
}

// Round 7
// 357.051 us; speedup vs baseline: 2.8109x; 1.0559x over previous
//
#include <hip/hip_runtime.h>
#include <hip/hip_bf16.h>

#define GG   256
#define NPGD 192
#define NN   (GG*NPGD)    // 49152 nodes
#define DDIM 128
#define EE   786432
#define HH   8

typedef __attribute__((ext_vector_type(8))) short short8;
typedef __attribute__((ext_vector_type(4))) float f32x4;
typedef __attribute__((ext_vector_type(4))) float f4v;
typedef __attribute__((ext_vector_type(4))) unsigned short u16x4;

__device__ __forceinline__ float bn_rsq() { return 0.9999950000374996f; } // 1/sqrt(1+1e-5)
__device__ __forceinline__ float bf2f(unsigned short u) { return __uint_as_float((unsigned)u << 16); }

// ---------------- prep: histogram (0..3071) | weight cvt (3072..3231) | xb=bf16(x) (3232..9375) ----------------
__global__ __launch_bounds__(256) void k_prep(
    const int* __restrict__ dst, int* __restrict__ cnt,
    const float* __restrict__ gw1, const float* __restrict__ gw2,
    const float* __restrict__ ipw, const float* __restrict__ opw,
    const float* __restrict__ fw1, const float* __restrict__ fw2,
    __hip_bfloat16* __restrict__ wb,
    const float* __restrict__ x, __hip_bfloat16* __restrict__ xb)
{
    const int b = blockIdx.x;
    if (b < 3072) {
        int e = b * 256 + threadIdx.x;
        atomicAdd(&cnt[dst[e]], 1);
        return;
    }
    if (b < 3232) {
        int g = (b - 3072) * 1024 + threadIdx.x * 4;
        const float* s; int off;
        if      (g <  16384) { s = gw1; off = 0; }
        else if (g <  32768) { s = gw2; off = 16384; }
        else if (g <  81920) { s = ipw; off = 32768; }
        else if (g <  98304) { s = opw; off = 81920; }
        else if (g < 131072) { s = fw1; off = 98304; }
        else                 { s = fw2; off = 131072; }
        float4 f = *(const float4*)&s[g - off];
        wb[g]     = __float2bfloat16(f.x);
        wb[g + 1] = __float2bfloat16(f.y);
        wb[g + 2] = __float2bfloat16(f.z);
        wb[g + 3] = __float2bfloat16(f.w);
        return;
    }
    int i = (b - 3232) * 1024 + threadIdx.x * 4;
    float4 f = *(const float4*)&x[i];
    ushort4 u;
    u.x = __bfloat16_as_ushort(__float2bfloat16(f.x));
    u.y = __bfloat16_as_ushort(__float2bfloat16(f.y));
    u.z = __bfloat16_as_ushort(__float2bfloat16(f.z));
    u.w = __bfloat16_as_ushort(__float2bfloat16(f.w));
    *(ushort4*)&xb[i] = u;
}

// ---------------- exclusive prefix scan over 49152 counts (1 block) ----------------
__global__ __launch_bounds__(1024) void k_scan(const int* __restrict__ cnt,
                                               int* __restrict__ offp, int* __restrict__ cur) {
    __shared__ int part[1024];
    const int t = threadIdx.x;
    const int4* c4 = (const int4*)cnt;
    int4 v[12];
    int s = 0;
#pragma unroll
    for (int i = 0; i < 12; ++i) {
        v[i] = c4[t * 12 + i];
        s += v[i].x + v[i].y + v[i].z + v[i].w;
    }
    part[t] = s;
    __syncthreads();
    for (int d = 1; d < 1024; d <<= 1) {
        int u = (t >= d) ? part[t - d] : 0;
        __syncthreads();
        part[t] += u;
        __syncthreads();
    }
    int pre = (t == 0) ? 0 : part[t - 1];
    int4* o4 = (int4*)offp;
    int4* u4 = (int4*)cur;
#pragma unroll
    for (int i = 0; i < 12; ++i) {
        int4 a = v[i], o;
        o.x = pre; pre += a.x;
        o.y = pre; pre += a.y;
        o.z = pre; pre += a.z;
        o.w = pre; pre += a.w;
        o4[t * 12 + i] = o;
        u4[t * 12 + i] = o;
    }
    if (t == 1023) offp[NN] = pre;
}

// ---------------- scatter: CSR payload {edge_id, src} ----------------
__global__ __launch_bounds__(256) void k_scatter(const int* __restrict__ dst, const int* __restrict__ src,
                                                 int* __restrict__ cur, int2* __restrict__ ecsr) {
    int e = blockIdx.x * 256 + threadIdx.x;
    int p = atomicAdd(&cur[dst[e]], 1);
    ecsr[p] = make_int2(e, src[e]);
}

// ---------------- GINE aggregate: z = bf16(x) + sum_in relu(xb[src]+e) ----------------
// half-wave per edge row (32 lanes x 16B); ea loads non-temporal (streamed once) to keep
// L2 for the xb gather set; self-term from xb.
__global__ __launch_bounds__(256, 8) void k_aggr(
    const __hip_bfloat16* __restrict__ xb,
    const float* __restrict__ ea,
    const int* __restrict__ offp, const int2* __restrict__ ecsr,
    __hip_bfloat16* __restrict__ z)
{
    const int tid = threadIdx.x;
    const int w = tid >> 6;
    const int v = blockIdx.x * 4 + w;
    const int half = (tid >> 5) & 1;
    const int c = (tid & 31) * 4;
    const int b = offp[v], e = offp[v + 1];
    const int n = e - b;
    const int nh = (n + 1) >> 1;
    const int s0 = b + (half ? nh : 0);
    const int end = half ? e : (b + nh);

    float ax = 0.f, ay = 0.f, az = 0.f, aw = 0.f;
    int i = s0;
    for (; i + 3 < end; i += 4) {
        const int2 p0 = ecsr[i];
        const int2 p1 = ecsr[i + 1];
        const int2 p2 = ecsr[i + 2];
        const int2 p3 = ecsr[i + 3];
        const f4v   a0 = __builtin_nontemporal_load((const f4v*)&ea[(size_t)p0.x * DDIM + c]);
        const u16x4 s0v = *(const u16x4*)&xb[(size_t)p0.y * DDIM + c];
        const f4v   a1 = __builtin_nontemporal_load((const f4v*)&ea[(size_t)p1.x * DDIM + c]);
        const u16x4 s1v = *(const u16x4*)&xb[(size_t)p1.y * DDIM + c];
        const f4v   a2 = __builtin_nontemporal_load((const f4v*)&ea[(size_t)p2.x * DDIM + c]);
        const u16x4 s2v = *(const u16x4*)&xb[(size_t)p2.y * DDIM + c];
        const f4v   a3 = __builtin_nontemporal_load((const f4v*)&ea[(size_t)p3.x * DDIM + c]);
        const u16x4 s3v = *(const u16x4*)&xb[(size_t)p3.y * DDIM + c];
        ax += fmaxf(a0[0] + bf2f(s0v[0]), 0.f) + fmaxf(a1[0] + bf2f(s1v[0]), 0.f)
            + fmaxf(a2[0] + bf2f(s2v[0]), 0.f) + fmaxf(a3[0] + bf2f(s3v[0]), 0.f);
        ay += fmaxf(a0[1] + bf2f(s0v[1]), 0.f) + fmaxf(a1[1] + bf2f(s1v[1]), 0.f)
            + fmaxf(a2[1] + bf2f(s2v[1]), 0.f) + fmaxf(a3[1] + bf2f(s3v[1]), 0.f);
        az += fmaxf(a0[2] + bf2f(s0v[2]), 0.f) + fmaxf(a1[2] + bf2f(s1v[2]), 0.f)
            + fmaxf(a2[2] + bf2f(s2v[2]), 0.f) + fmaxf(a3[2] + bf2f(s3v[2]), 0.f);
        aw += fmaxf(a0[3] + bf2f(s0v[3]), 0.f) + fmaxf(a1[3] + bf2f(s1v[3]), 0.f)
            + fmaxf(a2[3] + bf2f(s2v[3]), 0.f) + fmaxf(a3[3] + bf2f(s3v[3]), 0.f);
    }
    for (; i < end; ++i) {
        const int2 p0 = ecsr[i];
        const f4v   a0 = __builtin_nontemporal_load((const f4v*)&ea[(size_t)p0.x * DDIM + c]);
        const u16x4 s0v = *(const u16x4*)&xb[(size_t)p0.y * DDIM + c];
        ax += fmaxf(a0[0] + bf2f(s0v[0]), 0.f);
        ay += fmaxf(a0[1] + bf2f(s0v[1]), 0.f);
        az += fmaxf(a0[2] + bf2f(s0v[2]), 0.f);
        aw += fmaxf(a0[3] + bf2f(s0v[3]), 0.f);
    }
    ax += __shfl_xor(ax, 32);
    ay += __shfl_xor(ay, 32);
    az += __shfl_xor(az, 32);
    aw += __shfl_xor(aw, 32);

    if (half == 0) {
        const u16x4 xv = *(const u16x4*)&xb[(size_t)v * DDIM + c];
        ushort4 u;
        u.x = __bfloat16_as_ushort(__float2bfloat16(bf2f(xv[0]) + ax));
        u.y = __bfloat16_as_ushort(__float2bfloat16(bf2f(xv[1]) + ay));
        u.z = __bfloat16_as_ushort(__float2bfloat16(bf2f(xv[2]) + az));
        u.w = __bfloat16_as_ushort(__float2bfloat16(bf2f(xv[3]) + aw));
        *(ushort4*)&z[(size_t)v * DDIM + c] = u;
    }
}

// ---------------- fused2: attention+in_proj (blocks 0..2047) | GIN MLP (2048..2815) ----------------
__global__ __launch_bounds__(256) void k_fused2(
    const __hip_bfloat16* __restrict__ xb,
    const __hip_bfloat16* __restrict__ ipw, const float* __restrict__ ipb,
    __hip_bfloat16* __restrict__ o,
    const __hip_bfloat16* __restrict__ zb,
    const __hip_bfloat16* __restrict__ W1, const float* __restrict__ b1,
    const __hip_bfloat16* __restrict__ W2, const float* __restrict__ b2,
    const float* __restrict__ xres,
    const float* __restrict__ bng, const float* __restrict__ bnb,
    __hip_bfloat16* __restrict__ hl)
{
    __shared__ __align__(16) char smem[50432];
    const int tid = threadIdx.x;
    const int l = tid & 63, w = tid >> 6;
    const int cl = l & 15;
    const int kg = (l >> 4) * 8;
    const int rg = (l >> 4) * 4;

    if (blockIdx.x < 2048) {
        // ---- attention for (g, h), in_proj fused (disjoint head slice)
        const int g = blockIdx.x >> 3, h = blockIdx.x & 7;
        __hip_bfloat16* Ql = (__hip_bfloat16*)smem;             // 192*24*2 = 9216 B
        __hip_bfloat16* Kl = (__hip_bfloat16*)(smem + 9216);    // 9216 B
        __hip_bfloat16* Vt = (__hip_bfloat16*)(smem + 18432);   // 16*200*2 = 6400 B
        __hip_bfloat16* Pl = (__hip_bfloat16*)(smem + 24832);   // 4*16*200*2 = 25600 B
        const __hip_bfloat16* xg = xb + (size_t)g * NPGD * DDIM;
        const int gq = l >> 4;

        // q/k/v slice for this head: [192 x 16] each; wave w owns row-tiles {w, w+4, w+8}
        // Q gets 0.25*log2(e) folded in -> softmax uses exp2 (v_exp_f32 is natively 2^x)
        const float QSC = 0.36067376022224085f;
        const float biq = ipb[h * 16 + cl];
        const float bik = ipb[128 + h * 16 + cl];
        const float biv = ipb[256 + h * 16 + cl];
        for (int mt = w; mt < 12; mt += 4) {
            short8 afr[4];
#pragma unroll
            for (int f = 0; f < 4; ++f)
                afr[f] = *(const short8*)&xg[(size_t)(mt * 16 + cl) * DDIM + f * 32 + kg];
            f32x4 qa = {0.f, 0.f, 0.f, 0.f}, ka = {0.f, 0.f, 0.f, 0.f}, va = {0.f, 0.f, 0.f, 0.f};
#pragma unroll
            for (int f = 0; f < 4; ++f) {
                short8 bq = *(const short8*)&ipw[(size_t)(h * 16 + cl) * DDIM + f * 32 + kg];
                short8 bk = *(const short8*)&ipw[(size_t)(128 + h * 16 + cl) * DDIM + f * 32 + kg];
                short8 bv = *(const short8*)&ipw[(size_t)(256 + h * 16 + cl) * DDIM + f * 32 + kg];
                qa = __builtin_amdgcn_mfma_f32_16x16x32_bf16(afr[f], bq, qa, 0, 0, 0);
                ka = __builtin_amdgcn_mfma_f32_16x16x32_bf16(afr[f], bk, ka, 0, 0, 0);
                va = __builtin_amdgcn_mfma_f32_16x16x32_bf16(afr[f], bv, va, 0, 0, 0);
            }
#pragma unroll
            for (int j = 0; j < 4; ++j) {
                const int r = mt * 16 + rg + j;
                Ql[r * 24 + cl] = __float2bfloat16((qa[j] + biq) * QSC);
                Kl[r * 24 + cl] = __float2bfloat16(ka[j] + bik);
                Vt[cl * 200 + r] = __float2bfloat16(va[j] + biv);
            }
        }
        __syncthreads();

        for (int it = 0; it < 3; ++it) {
            const int qt = w + it * 4;
            short8 aq = {0, 0, 0, 0, 0, 0, 0, 0};
            if (gq < 2)
                aq = *(const short8*)&Ql[(qt * 16 + cl) * 24 + gq * 8];

            f32x4 s[12];
#pragma unroll
            for (int kt = 0; kt < 12; ++kt) {
                short8 bk = {0, 0, 0, 0, 0, 0, 0, 0};
                if (gq < 2)
                    bk = *(const short8*)&Kl[(kt * 16 + cl) * 24 + gq * 8];
                f32x4 zz = {0.f, 0.f, 0.f, 0.f};
                s[kt] = __builtin_amdgcn_mfma_f32_16x16x32_bf16(aq, bk, zz, 0, 0, 0);
            }

            float mj[4], sj[4];
#pragma unroll
            for (int j = 0; j < 4; ++j) {
                float mm = -3.0e38f;
#pragma unroll
                for (int kt = 0; kt < 12; ++kt) mm = fmaxf(mm, s[kt][j]);
                mm = fmaxf(mm, __shfl_xor(mm, 1));
                mm = fmaxf(mm, __shfl_xor(mm, 2));
                mm = fmaxf(mm, __shfl_xor(mm, 4));
                mm = fmaxf(mm, __shfl_xor(mm, 8));
                mj[j] = mm;
            }
#pragma unroll
            for (int j = 0; j < 4; ++j) {
                float sum = 0.f;
#pragma unroll
                for (int kt = 0; kt < 12; ++kt) {
                    float p = exp2f(s[kt][j] - mj[j]);
                    s[kt][j] = p;
                    sum += p;
                }
                sum += __shfl_xor(sum, 1);
                sum += __shfl_xor(sum, 2);
                sum += __shfl_xor(sum, 4);
                sum += __shfl_xor(sum, 8);
                sj[j] = 1.f / sum;
            }
#pragma unroll
            for (int kt = 0; kt < 12; ++kt)
#pragma unroll
                for (int j = 0; j < 4; ++j)
                    Pl[w * 3200 + (gq * 4 + j) * 200 + kt * 16 + cl] = __float2bfloat16(s[kt][j] * sj[j]);
            __syncthreads();

            f32x4 oa = {0.f, 0.f, 0.f, 0.f};
#pragma unroll
            for (int kt = 0; kt < 6; ++kt) {
                short8 ap = *(const short8*)&Pl[w * 3200 + cl * 200 + kt * 32 + gq * 8];
                short8 av = *(const short8*)&Vt[cl * 200 + kt * 32 + gq * 8];
                oa = __builtin_amdgcn_mfma_f32_16x16x32_bf16(ap, av, oa, 0, 0, 0);
            }
#pragma unroll
            for (int j = 0; j < 4; ++j)
                o[((size_t)g * NPGD + qt * 16 + gq * 4 + j) * DDIM + h * 16 + cl] = __float2bfloat16(oa[j]);
            __syncthreads();
        }
        return;
    }

    // ---- GIN MLP: hl = bn1l(x + relu(zb@W1^T+b1)@W2^T + b2)
    const int bid = blockIdx.x - 2048;
    __hip_bfloat16* hid = (__hip_bfloat16*)smem;               // 4*16*152*2 = 19456 B
    const int row0 = bid * 64 + w * 16;

    short8 af[4];
#pragma unroll
    for (int f = 0; f < 4; ++f)
        af[f] = *(const short8*)&zb[(size_t)(row0 + cl) * DDIM + f * 32 + kg];

#pragma unroll
    for (int ct = 0; ct < 8; ++ct) {
        f32x4 acc = {0.f, 0.f, 0.f, 0.f};
#pragma unroll
        for (int f = 0; f < 4; ++f) {
            short8 bf = *(const short8*)&W1[(size_t)(ct * 16 + cl) * DDIM + f * 32 + kg];
            acc = __builtin_amdgcn_mfma_f32_16x16x32_bf16(af[f], bf, acc, 0, 0, 0);
        }
        const float bv = b1[ct * 16 + cl];
#pragma unroll
        for (int j = 0; j < 4; ++j)
            hid[w * 2432 + (rg + j) * 152 + ct * 16 + cl] = __float2bfloat16(fmaxf(acc[j] + bv, 0.f));
    }
    __syncthreads();

    short8 af2[4];
#pragma unroll
    for (int f = 0; f < 4; ++f)
        af2[f] = *(const short8*)&hid[w * 2432 + cl * 152 + f * 32 + kg];

#pragma unroll
    for (int ct = 0; ct < 8; ++ct) {
        f32x4 acc = {0.f, 0.f, 0.f, 0.f};
#pragma unroll
        for (int f = 0; f < 4; ++f) {
            short8 bf = *(const short8*)&W2[(size_t)(ct * 16 + cl) * DDIM + f * 32 + kg];
            acc = __builtin_amdgcn_mfma_f32_16x16x32_bf16(af2[f], bf, acc, 0, 0, 0);
        }
        const int c = ct * 16 + cl;
        const float bv = b2[c];
#pragma unroll
        for (int j = 0; j < 4; ++j) {
            const int r = row0 + rg + j;
            float v = acc[j] + bv + xres[(size_t)r * DDIM + c];
            v = bng[c] * v * bn_rsq() + bnb[c];
            hl[(size_t)r * DDIM + c] = __float2bfloat16(v);
        }
    }
}

// ---------------- tail: out_proj + bn1g + merge + FFN + bn2 -> d_out (fp32) ----------------
__global__ __launch_bounds__(256) void k_tail(
    const __hip_bfloat16* __restrict__ o,
    const __hip_bfloat16* __restrict__ opw, const float* __restrict__ opb,
    const float* __restrict__ x, const __hip_bfloat16* __restrict__ hl,
    const float* __restrict__ b1gg, const float* __restrict__ b1gb,
    const __hip_bfloat16* __restrict__ fw1, const float* __restrict__ fb1,
    const __hip_bfloat16* __restrict__ fw2, const float* __restrict__ fb2,
    const float* __restrict__ b2g, const float* __restrict__ b2b,
    float* __restrict__ out)
{
    __shared__ __align__(16) __hip_bfloat16 hbuf[4][16 * 136];  // h tile (bf16)
    __shared__ __align__(16) __hip_bfloat16 hid[4][16 * 280];   // ffn hidden
    const int tid = threadIdx.x;
    const int l = tid & 63, w = tid >> 6;
    const int row0 = blockIdx.x * 64 + w * 16;
    const int cl = l & 15;
    const int kg = (l >> 4) * 8;
    const int rg = (l >> 4) * 4;

    // stage 1: h = bn1g(x + o@opw^T + opb) + hl   (kept fp32 in hreg)
    short8 af[4];
#pragma unroll
    for (int f = 0; f < 4; ++f)
        af[f] = *(const short8*)&o[(size_t)(row0 + cl) * DDIM + f * 32 + kg];

    float hreg[32];
#pragma unroll
    for (int ct = 0; ct < 8; ++ct) {
        f32x4 acc = {0.f, 0.f, 0.f, 0.f};
#pragma unroll
        for (int f = 0; f < 4; ++f) {
            short8 bf = *(const short8*)&opw[(size_t)(ct * 16 + cl) * DDIM + f * 32 + kg];
            acc = __builtin_amdgcn_mfma_f32_16x16x32_bf16(af[f], bf, acc, 0, 0, 0);
        }
        const int c = ct * 16 + cl;
        const float bv = opb[c];
#pragma unroll
        for (int j = 0; j < 4; ++j) {
            const int r = row0 + rg + j;
            float v = acc[j] + bv + x[(size_t)r * DDIM + c];
            v = b1gg[c] * v * bn_rsq() + b1gb[c];
            v += __bfloat162float(hl[(size_t)r * DDIM + c]);
            hreg[ct * 4 + j] = v;
            hbuf[w][(rg + j) * 136 + c] = __float2bfloat16(v);
        }
    }
    __syncthreads();

    // stage 2: hid = relu(h @ fw1^T + fb1)
    short8 af2[4];
#pragma unroll
    for (int f = 0; f < 4; ++f)
        af2[f] = *(const short8*)&hbuf[w][cl * 136 + f * 32 + kg];

#pragma unroll
    for (int ct = 0; ct < 16; ++ct) {
        f32x4 acc = {0.f, 0.f, 0.f, 0.f};
#pragma unroll
        for (int f = 0; f < 4; ++f) {
            short8 bf = *(const short8*)&fw1[(size_t)(ct * 16 + cl) * DDIM + f * 32 + kg];
            acc = __builtin_amdgcn_mfma_f32_16x16x32_bf16(af2[f], bf, acc, 0, 0, 0);
        }
        const float bv = fb1[ct * 16 + cl];
#pragma unroll
        for (int j = 0; j < 4; ++j)
            hid[w][(rg + j) * 280 + ct * 16 + cl] = __float2bfloat16(fmaxf(acc[j] + bv, 0.f));
    }
    __syncthreads();

    // stage 3: out = bn2(h + hid @ fw2^T + fb2)
    short8 af3[8];
#pragma unroll
    for (int f = 0; f < 8; ++f)
        af3[f] = *(const short8*)&hid[w][cl * 280 + f * 32 + kg];

#pragma unroll
    for (int ct = 0; ct < 8; ++ct) {
        f32x4 acc = {0.f, 0.f, 0.f, 0.f};
#pragma unroll
        for (int f = 0; f < 8; ++f) {
            short8 bf = *(const short8*)&fw2[(size_t)(ct * 16 + cl) * 256 + f * 32 + kg];
            acc = __builtin_amdgcn_mfma_f32_16x16x32_bf16(af3[f], bf, acc, 0, 0, 0);
        }
        const int c = ct * 16 + cl;
        const float bv = fb2[c];
#pragma unroll
        for (int j = 0; j < 4; ++j) {
            const int r = row0 + rg + j;
            float v = acc[j] + bv + hreg[ct * 4 + j];
            v = b2g[c] * v * bn_rsq() + b2b[c];
            out[(size_t)r * DDIM + c] = v;
        }
    }
}

// ---------------- launch ----------------
extern "C" void kernel_launch(void* const* d_in, const int* in_sizes, int n_in,
                              void* d_out, int out_size, void* d_ws, size_t ws_size,
                              hipStream_t stream) {
    (void)in_sizes; (void)n_in; (void)out_size; (void)ws_size;
    const float* x    = (const float*)d_in[0];
    const float* ea   = (const float*)d_in[1];
    const int*   ei   = (const int*)d_in[2];
    const float* gw1  = (const float*)d_in[3];
    const float* gb1  = (const float*)d_in[4];
    const float* gw2  = (const float*)d_in[5];
    const float* gb2  = (const float*)d_in[6];
    const float* ipw  = (const float*)d_in[7];
    const float* ipb  = (const float*)d_in[8];
    const float* opw  = (const float*)d_in[9];
    const float* opb  = (const float*)d_in[10];
    const float* b1lg = (const float*)d_in[11];
    const float* b1lb = (const float*)d_in[12];
    const float* b1gg = (const float*)d_in[13];
    const float* b1gb = (const float*)d_in[14];
    const float* b2g  = (const float*)d_in[15];
    const float* b2b  = (const float*)d_in[16];
    const float* fw1  = (const float*)d_in[17];
    const float* fb1  = (const float*)d_in[18];
    const float* fw2  = (const float*)d_in[19];
    const float* fb2  = (const float*)d_in[20];

    char* ws = (char*)d_ws;
    size_t off = 0;
    auto alloc = [&](size_t b) -> char* {
        char* p = ws + off;
        off = (off + b + 255) & ~(size_t)255;
        return p;
    };
    int*  cnt  = (int*)alloc((NN + 1) * 4);
    int*  offp = (int*)alloc((NN + 1) * 4);
    int*  cur  = (int*)alloc((NN + 1) * 4);
    __hip_bfloat16* wbuf = (__hip_bfloat16*)alloc(163840 * 2);
    int2* ecsr = (int2*)alloc((size_t)EE * 8);
    __hip_bfloat16* xb  = (__hip_bfloat16*)alloc((size_t)NN * DDIM * 2);
    __hip_bfloat16* zb  = (__hip_bfloat16*)alloc((size_t)NN * DDIM * 2);
    __hip_bfloat16* g1  = (__hip_bfloat16*)alloc((size_t)NN * DDIM * 2);  // attn out
    __hip_bfloat16* hl  = (__hip_bfloat16*)alloc((size_t)NN * DDIM * 2);  // h_local

    __hip_bfloat16* w1b  = wbuf;
    __hip_bfloat16* w2b  = wbuf + 16384;
    __hip_bfloat16* ipwb = wbuf + 32768;
    __hip_bfloat16* opwb = wbuf + 81920;
    __hip_bfloat16* f1b  = wbuf + 98304;
    __hip_bfloat16* f2bw = wbuf + 131072;

    const int* srcI = ei;
    const int* dstI = ei + EE;

    hipMemsetAsync(cnt, 0, (NN + 1) * 4, stream);
    k_prep<<<9376, 256, 0, stream>>>(dstI, cnt, gw1, gw2, ipw, opw, fw1, fw2, wbuf, x, xb);
    k_scan<<<1, 1024, 0, stream>>>(cnt, offp, cur);
    k_scatter<<<EE / 256, 256, 0, stream>>>(dstI, srcI, cur, ecsr);
    // aggregation (nt ea stream, bf16 gather, self-term from xb) -> zb
    k_aggr<<<NN / 4, 256, 0, stream>>>(xb, ea, offp, ecsr, zb);
    // attention (with fused in_proj) || GIN MLP
    k_fused2<<<2048 + 768, 256, 0, stream>>>(xb, ipwb, ipb, g1, zb, w1b, gb1, w2b, gb2,
                                             x, b1lg, b1lb, hl);
    // out_proj + bn1g + merge + FFN + bn2
    k_tail<<<NN / 64, 256, 0, stream>>>(g1, opwb, opb, x, hl, b1gg, b1gb,
                                        f1b, fb1, f2bw, fb2, b2g, b2b, (float*)d_out);
}